// Round 3
// baseline (413.007 us; speedup 1.0000x reference)
//
#include <hip/hip_runtime.h>
#include <hip/hip_bf16.h>

// Problem constants (match reference)
#define NN 20000
#define EE 640000
#define DD 256
#define GG 64
#define ETOT (EE + NN)   // edges + self loops = 660000
#define BN_EPS 1e-5f

typedef short s16x8 __attribute__((ext_vector_type(8)));
typedef float f32x4 __attribute__((ext_vector_type(4)));

__device__ __forceinline__ unsigned short f2bf_hi(float x) {
    unsigned u = __float_as_uint(x);
    unsigned r = (u + 0x7FFFu + ((u >> 16) & 1u)) >> 16;   // RNE
    return (unsigned short)r;
}
__device__ __forceinline__ float bf2f(unsigned short h) {
    return __uint_as_float(((unsigned)h) << 16);
}

// ---------------------------------------------------------------------------
// Graph-boundary prep: batch is SORTED -> binary search, no atomics.
// ---------------------------------------------------------------------------
__global__ void prep_kernel(const int* __restrict__ batch, int* __restrict__ start,
                            float* __restrict__ cntf) {
    int g = threadIdx.x;
    if (g <= GG) {
        if (g == GG) start[GG] = NN;
        else {
            int lo = 0, hi = NN;
            while (lo < hi) { int mid = (lo + hi) >> 1; if (batch[mid] < g) lo = mid + 1; else hi = mid; }
            start[g] = lo;
        }
    }
    __syncthreads();
    if (g < GG) cntf[g] = (float)(start[g + 1] - start[g]);
}

// ---------------------------------------------------------------------------
// CSR build: histogram -> scan -> scatter (grouped by destination node)
// ---------------------------------------------------------------------------
__global__ void hist_kernel(const int* __restrict__ ei, int* __restrict__ counts) {
    int i = blockIdx.x * blockDim.x + threadIdx.x;
    int stride = gridDim.x * blockDim.x;
    for (; i < ETOT; i += stride) {
        int dst = (i < EE) ? ei[EE + i] : (i - EE);
        atomicAdd(&counts[dst], 1);
    }
}

__global__ __launch_bounds__(1024) void scan_kernel(const int* __restrict__ counts,
                                                    int* __restrict__ offsets,
                                                    int* __restrict__ cursor) {
    __shared__ int wsum[16];
    __shared__ int carry_s;
    int tid = threadIdx.x, lane = tid & 63, wid = tid >> 6;
    if (tid == 0) carry_s = 0;
    __syncthreads();
    for (int base = 0; base < NN; base += 1024) {
        int i = base + tid;
        int v = (i < NN) ? counts[i] : 0;
        int x = v;
        #pragma unroll
        for (int o = 1; o < 64; o <<= 1) { int t = __shfl_up(x, o, 64); if (lane >= o) x += t; }
        if (lane == 63) wsum[wid] = x;
        __syncthreads();
        if (wid == 0) {
            int wv = (lane < 16) ? wsum[lane] : 0;
            #pragma unroll
            for (int o = 1; o < 16; o <<= 1) { int t = __shfl_up(wv, o, 64); if (lane >= o) wv += t; }
            if (lane < 16) wsum[lane] = wv;   // inclusive over wave sums
        }
        __syncthreads();
        int wbase = wid ? wsum[wid - 1] : 0;
        int carry = carry_s;
        if (i < NN) {
            int ex = carry + wbase + x - v;   // exclusive
            offsets[i] = ex;
            cursor[i] = ex;
        }
        __syncthreads();
        if (tid == 0) carry_s = carry + wsum[15];
        __syncthreads();
    }
    if (threadIdx.x == 0) offsets[NN] = carry_s;
}

__global__ void scatter_kernel(const int* __restrict__ ei, int* __restrict__ cursor,
                               int* __restrict__ csr_src) {
    int i = blockIdx.x * blockDim.x + threadIdx.x;
    int stride = gridDim.x * blockDim.x;
    for (; i < ETOT; i += stride) {
        int s, d;
        if (i < EE) { s = ei[i]; d = ei[EE + i]; }
        else        { s = i - EE; d = i - EE; }
        int pos = atomicAdd(&cursor[d], 1);
        csr_src[pos] = s;
    }
}

// ---------------------------------------------------------------------------
// Weight conversion (both layers in one launch):
// W[k][n] fp32 -> BhT/BlT [n][k] bf16 (hi + residual-lo)
// ---------------------------------------------------------------------------
__global__ __launch_bounds__(256) void convB_kernel(const float* __restrict__ W1,
                                                    const float* __restrict__ W2,
                                                    short* __restrict__ BhT1,
                                                    short* __restrict__ BlT1,
                                                    short* __restrict__ BhT2,
                                                    short* __restrict__ BlT2) {
    int b = blockIdx.x;
    int n = b & 255, which = b >> 8;
    int k = threadIdx.x;
    const float* B = which ? W2 : W1;
    short* Bh = which ? BhT2 : BhT1;
    short* Bl = which ? BlT2 : BlT1;
    float x = B[k * DD + n];
    unsigned short hb = f2bf_hi(x);
    Bh[n * DD + k] = (short)hb;
    Bl[n * DD + k] = (short)f2bf_hi(x - bf2f(hb));
}

// ---------------------------------------------------------------------------
// MFMA GEMM: h = A[M x 256] @ W[256 x 256], split-bf16 3-pass.
// Outputs: hb (bf16 h, for the gather) and fused as_/ad_ = h.a_src / h.a_dst
// (computed from exact fp32 accumulators, atomicAdd across the 2 col-blocks).
// 128x128 tile, BK=64, 4 waves (2x2), 16x16x32 bf16 MFMA, XOR-swizzled LDS.
// ---------------------------------------------------------------------------
#define GBM 128
#define GBN 128
#define GBK 64

__global__ __launch_bounds__(256) void gemm_mfma_kernel(const float* __restrict__ A,
                                                        const short* __restrict__ BhT,
                                                        const short* __restrict__ BlT,
                                                        const float* __restrict__ a_src,
                                                        const float* __restrict__ a_dst,
                                                        short* __restrict__ hb,
                                                        float* __restrict__ as_,
                                                        float* __restrict__ ad_,
                                                        int M) {
    __shared__ short As_h[GBM * GBK];
    __shared__ short As_l[GBM * GBK];
    __shared__ short Bs_h[GBN * GBK];
    __shared__ short Bs_l[GBN * GBK];
    int tid = threadIdx.x;
    int row0 = blockIdx.y * GBM;
    int col0 = blockIdx.x * GBN;
    int w = tid >> 6, lane = tid & 63;
    int wr = w >> 1, wc = w & 1;

    f32x4 acc[4][4];
    #pragma unroll
    for (int m = 0; m < 4; ++m)
        #pragma unroll
        for (int n = 0; n < 4; ++n)
            acc[m][n] = (f32x4){0.f, 0.f, 0.f, 0.f};

    int srow = tid >> 3;     // 0..31
    int sslot = tid & 7;     // 0..7  (16B slot within a 128B row)

    for (int k0 = 0; k0 < DD; k0 += GBK) {
        __syncthreads();
        #pragma unroll
        for (int p = 0; p < 4; ++p) {
            int r = p * 32 + srow;
            int gr = row0 + r;
            float xv[8];
            if (gr < M) {
                const float4* ap = (const float4*)(A + (size_t)gr * DD + k0 + sslot * 8);
                float4 a0 = ap[0], a1 = ap[1];
                xv[0] = a0.x; xv[1] = a0.y; xv[2] = a0.z; xv[3] = a0.w;
                xv[4] = a1.x; xv[5] = a1.y; xv[6] = a1.z; xv[7] = a1.w;
            } else {
                #pragma unroll
                for (int i = 0; i < 8; ++i) xv[i] = 0.f;
            }
            s16x8 hv, lv;
            #pragma unroll
            for (int i = 0; i < 8; ++i) {
                unsigned short hbb = f2bf_hi(xv[i]);
                hv[i] = (short)hbb;
                lv[i] = (short)f2bf_hi(xv[i] - bf2f(hbb));
            }
            int byte = r * 128 + ((sslot ^ (r & 7)) << 4);
            *(s16x8*)((char*)As_h + byte) = hv;
            *(s16x8*)((char*)As_l + byte) = lv;
            const short* bhp = BhT + (size_t)(col0 + r) * DD + k0 + sslot * 8;
            const short* blp = BlT + (size_t)(col0 + r) * DD + k0 + sslot * 8;
            *(s16x8*)((char*)Bs_h + byte) = *(const s16x8*)bhp;
            *(s16x8*)((char*)Bs_l + byte) = *(const s16x8*)blp;
        }
        __syncthreads();

        #pragma unroll
        for (int ks = 0; ks < 2; ++ks) {
            s16x8 ah[4], al[4], bh[4], bl[4];
            int g = ks * 4 + (lane >> 4);
            #pragma unroll
            for (int m = 0; m < 4; ++m) {
                int r = wr * 64 + m * 16 + (lane & 15);
                int byte = r * 128 + ((g ^ (r & 7)) << 4);
                ah[m] = *(const s16x8*)((char*)As_h + byte);
                al[m] = *(const s16x8*)((char*)As_l + byte);
            }
            #pragma unroll
            for (int n = 0; n < 4; ++n) {
                int c = wc * 64 + n * 16 + (lane & 15);
                int byte = c * 128 + ((g ^ (c & 7)) << 4);
                bh[n] = *(const s16x8*)((char*)Bs_h + byte);
                bl[n] = *(const s16x8*)((char*)Bs_l + byte);
            }
            #pragma unroll
            for (int m = 0; m < 4; ++m)
                #pragma unroll
                for (int n = 0; n < 4; ++n) {
                    acc[m][n] = __builtin_amdgcn_mfma_f32_16x16x32_bf16(ah[m], bh[n], acc[m][n], 0, 0, 0);
                    acc[m][n] = __builtin_amdgcn_mfma_f32_16x16x32_bf16(ah[m], bl[n], acc[m][n], 0, 0, 0);
                    acc[m][n] = __builtin_amdgcn_mfma_f32_16x16x32_bf16(al[m], bh[n], acc[m][n], 0, 0, 0);
                }
        }
    }

    // ---- fused matvec: per-row partial dots with a_src/a_dst ----
    float vsrc[4], vdst[4];
    #pragma unroll
    for (int n = 0; n < 4; ++n) {
        int cg = col0 + wc * 64 + n * 16 + (lane & 15);
        vsrc[n] = a_src[cg];
        vdst[n] = a_dst[cg];
    }
    #pragma unroll
    for (int m = 0; m < 4; ++m) {
        #pragma unroll
        for (int j = 0; j < 4; ++j) {
            float ps = 0.f, pd = 0.f;
            #pragma unroll
            for (int n = 0; n < 4; ++n) {
                float c = acc[m][n][j];
                ps += c * vsrc[n];
                pd += c * vdst[n];
            }
            #pragma unroll
            for (int o = 1; o < 16; o <<= 1) {
                ps += __shfl_xor(ps, o, 64);
                pd += __shfl_xor(pd, o, 64);
            }
            if ((lane & 15) == 0) {
                int rg = row0 + wr * 64 + m * 16 + ((lane >> 4) << 2) + j;
                if (rg < M) {
                    atomicAdd(&as_[rg], ps);
                    atomicAdd(&ad_[rg], pd);
                }
            }
        }
    }

    // ---- bf16 h output (C/D layout: col=lane&15, row=(lane>>4)*4+reg) ----
    #pragma unroll
    for (int m = 0; m < 4; ++m) {
        int rbase = row0 + wr * 64 + m * 16 + ((lane >> 4) << 2);
        #pragma unroll
        for (int n = 0; n < 4; ++n) {
            int cg = col0 + wc * 64 + n * 16 + (lane & 15);
            #pragma unroll
            for (int j = 0; j < 4; ++j) {
                int rg = rbase + j;
                if (rg < M) hb[(size_t)rg * DD + cg] = (short)f2bf_hi(acc[m][n][j]);
            }
        }
    }
}

// ---------------------------------------------------------------------------
// Aggregation: wave per (node, 64-feature slice), online softmax, bf16 gather.
// slice = blockIdx % 4 so each XCD (blockIdx % 8 round-robin) touches ONE
// 2.5 MB h-slice -> L2-resident. nt loads/stores keep streams out of L2.
// ---------------------------------------------------------------------------
__global__ __launch_bounds__(256) void aggregate_kernel(const short* __restrict__ hb,
                                                        const int* __restrict__ csr_src,
                                                        const int* __restrict__ offsets,
                                                        const float* __restrict__ as_,
                                                        const float* __restrict__ ad_,
                                                        const float* __restrict__ bias,
                                                        float* __restrict__ out) {
    int tid = threadIdx.x;
    int w = tid >> 6, lane = tid & 63;
    int b = blockIdx.x;
    int sl = b & 3;
    int node = ((b >> 2) << 2) + w;
    int f = sl * 64 + lane;
    int off = offsets[node];
    int deg = offsets[node + 1] - off;
    float adn = ad_[node];

    float m = -INFINITY, s = 0.f, acc = 0.f;
    for (int cs = 0; cs < deg; cs += 64) {
        int cl = min(64, deg - cs);
        float e = -INFINITY;
        int sidx = 0;
        if (lane < cl) {
            sidx = __builtin_nontemporal_load(csr_src + off + cs + lane);
            float t = as_[sidx] + adn;
            e = (t > 0.f) ? t : 0.2f * t;
        }
        float cm = e;
        #pragma unroll
        for (int o = 32; o > 0; o >>= 1) cm = fmaxf(cm, __shfl_xor(cm, o, 64));
        float newm = fmaxf(m, cm);
        float scale = expf(m - newm);           // exp(-inf)==0 on first chunk
        float ex = (lane < cl) ? expf(e - newm) : 0.f;
        float csum = ex;
        #pragma unroll
        for (int o = 32; o > 0; o >>= 1) csum += __shfl_xor(csum, o, 64);
        s = s * scale + csum;
        acc *= scale;
        for (int j = 0; j < cl; ++j) {
            float a = __shfl(ex, j, 64);
            int si = __shfl(sidx, j, 64);
            acc += a * bf2f((unsigned short)hb[si * DD + f]);
        }
        m = newm;
    }
    float r = acc / s + bias[f];
    r = (r > 0.f) ? r : 0.01f * r;
    __builtin_nontemporal_store(r, &out[(size_t)node * DD + f]);
}

// ---------------------------------------------------------------------------
// Pool: segment sums over sorted node ranges (BN folded into final)
// ---------------------------------------------------------------------------
#define PSLICE 8
__global__ __launch_bounds__(256) void pool_kernel(const float* __restrict__ h,
                                                   const int* __restrict__ start,
                                                   float* __restrict__ pool) {
    int g = blockIdx.x >> 3, sl = blockIdx.x & (PSLICE - 1);
    int f = threadIdx.x;
    int s0 = start[g], s1 = start[g + 1];
    float acc = 0.f;
    for (int nd = s0 + sl; nd < s1; nd += PSLICE)
        acc += h[(size_t)nd * DD + f];
    if (acc != 0.f || sl == 0) atomicAdd(&pool[g * DD + f], acc);
}

__global__ __launch_bounds__(256) void final_kernel(const float* __restrict__ pool,
                                                    const float* __restrict__ cnt,
                                                    const float* __restrict__ gam,
                                                    const float* __restrict__ bet,
                                                    const float* __restrict__ mean,
                                                    const float* __restrict__ var,
                                                    const float* __restrict__ Wl,
                                                    const float* __restrict__ bl,
                                                    float* __restrict__ out) {
    __shared__ float p_sh[DD];
    int g = blockIdx.x, j = threadIdx.x;
    float cn = cnt[g];
    float scale = gam[j] * rsqrtf(var[j] + BN_EPS);
    p_sh[j] = (cn > 0.f) ? (pool[g * DD + j] / cn - mean[j]) * scale + bet[j] : 0.f;
    __syncthreads();
    float acc = 0.f;
    for (int fi = 0; fi < DD; ++fi)
        acc += p_sh[fi] * Wl[j * DD + fi];
    out[g * DD + j] = acc + bl[j];
}

// ---------------------------------------------------------------------------
extern "C" void kernel_launch(void* const* d_in, const int* in_sizes, int n_in,
                              void* d_out, int out_size, void* d_ws, size_t ws_size,
                              hipStream_t stream) {
    const float* x       = (const float*)d_in[0];
    const int*   ei      = (const int*)d_in[1];
    const int*   batch   = (const int*)d_in[2];
    const float* W1      = (const float*)d_in[3];
    const float* a1_src  = (const float*)d_in[4];
    const float* a1_dst  = (const float*)d_in[5];
    const float* b1      = (const float*)d_in[6];
    const float* W2      = (const float*)d_in[7];
    const float* a2_src  = (const float*)d_in[8];
    const float* a2_dst  = (const float*)d_in[9];
    const float* b2      = (const float*)d_in[10];
    const float* bn_g    = (const float*)d_in[11];
    const float* bn_b    = (const float*)d_in[12];
    const float* bn_m    = (const float*)d_in[13];
    const float* bn_v    = (const float*)d_in[14];
    const float* Wl      = (const float*)d_in[15];
    const float* bl      = (const float*)d_in[16];
    float* out = (float*)d_out;

    char* ws = (char*)d_ws;
    size_t o = 0;
    auto take = [&](size_t bytes) { char* p = ws + o; o += (bytes + 255) & ~(size_t)255; return p; };
    int*   counts  = (int*)  take(NN * 4);
    int*   offsets = (int*)  take((NN + 1) * 4);
    int*   cursor  = (int*)  take(NN * 4);
    int*   csr_src = (int*)  take((size_t)ETOT * 4);
    float* as_     = (float*)take(NN * 4);
    float* ad_     = (float*)take(NN * 4);
    short* hb      = (short*)take((size_t)NN * DD * 2);
    float* bufB    = (float*)take((size_t)NN * DD * 4);
    float* pool    = (float*)take(GG * DD * 4);
    float* cnt     = (float*)take(GG * 4);
    int*   start   = (int*)  take((GG + 1) * 4);
    short* BhT1    = (short*)take((size_t)DD * DD * 2);
    short* BlT1    = (short*)take((size_t)DD * DD * 2);
    short* BhT2    = (short*)take((size_t)DD * DD * 2);
    short* BlT2    = (short*)take((size_t)DD * DD * 2);
    (void)ws_size; (void)in_sizes; (void)n_in; (void)out_size;

    hipMemsetAsync(counts, 0, NN * 4, stream);
    hipMemsetAsync(pool, 0, GG * DD * 4, stream);

    // prep + CSR build
    prep_kernel<<<1, 128, 0, stream>>>(batch, start, cnt);
    hist_kernel<<<2579, 256, 0, stream>>>(ei, counts);
    scan_kernel<<<1, 1024, 0, stream>>>(counts, offsets, cursor);
    scatter_kernel<<<2579, 256, 0, stream>>>(ei, cursor, csr_src);

    // weight conversions (both layers, one launch)
    convB_kernel<<<2 * DD, 256, 0, stream>>>(W1, W2, BhT1, BlT1, BhT2, BlT2);

    dim3 ggrid(DD / GBN, (NN + GBM - 1) / GBM);

    // ---- layer 1 ----
    hipMemsetAsync(as_, 0, NN * 4, stream);
    hipMemsetAsync(ad_, 0, NN * 4, stream);
    gemm_mfma_kernel<<<ggrid, 256, 0, stream>>>(x, BhT1, BlT1, a1_src, a1_dst, hb, as_, ad_, NN);
    aggregate_kernel<<<NN, 256, 0, stream>>>(hb, csr_src, offsets, as_, ad_, b1, bufB);

    // ---- layer 2 ----
    hipMemsetAsync(as_, 0, NN * 4, stream);
    hipMemsetAsync(ad_, 0, NN * 4, stream);
    gemm_mfma_kernel<<<ggrid, 256, 0, stream>>>(bufB, BhT2, BlT2, a2_src, a2_dst, hb, as_, ad_, NN);
    aggregate_kernel<<<NN, 256, 0, stream>>>(hb, csr_src, offsets, as_, ad_, b2, bufB);

    // ---- pool + BN + linear ----
    pool_kernel<<<GG * PSLICE, 256, 0, stream>>>(bufB, start, pool);
    final_kernel<<<GG, 256, 0, stream>>>(pool, cnt, bn_g, bn_b, bn_m, bn_v, Wl, bl, out);
}

// Round 4
// 387.598 us; speedup vs baseline: 1.0656x; 1.0656x over previous
//
#include <hip/hip_runtime.h>
#include <hip/hip_bf16.h>

// Problem constants (match reference)
#define NN 20000
#define EE 640000
#define DD 256
#define GG 64
#define ETOT (EE + NN)   // edges + self loops = 660000
#define BN_EPS 1e-5f

typedef short s16x8 __attribute__((ext_vector_type(8)));
typedef float f32x4 __attribute__((ext_vector_type(4)));

__device__ __forceinline__ unsigned short f2bf_hi(float x) {
    unsigned u = __float_as_uint(x);
    unsigned r = (u + 0x7FFFu + ((u >> 16) & 1u)) >> 16;   // RNE
    return (unsigned short)r;
}
__device__ __forceinline__ float bf2f(unsigned short h) {
    return __uint_as_float(((unsigned)h) << 16);
}

// ---------------------------------------------------------------------------
// Graph-boundary prep: batch is SORTED -> binary search, no atomics.
// ---------------------------------------------------------------------------
__global__ void prep_kernel(const int* __restrict__ batch, int* __restrict__ start,
                            float* __restrict__ cntf) {
    int g = threadIdx.x;
    if (g <= GG) {
        if (g == GG) start[GG] = NN;
        else {
            int lo = 0, hi = NN;
            while (lo < hi) { int mid = (lo + hi) >> 1; if (batch[mid] < g) lo = mid + 1; else hi = mid; }
            start[g] = lo;
        }
    }
    __syncthreads();
    if (g < GG) cntf[g] = (float)(start[g + 1] - start[g]);
}

// ---------------------------------------------------------------------------
// CSR build: histogram -> scan -> scatter (grouped by destination node)
// ---------------------------------------------------------------------------
__global__ void hist_kernel(const int* __restrict__ ei, int* __restrict__ counts) {
    int i = blockIdx.x * blockDim.x + threadIdx.x;
    int stride = gridDim.x * blockDim.x;
    for (; i < ETOT; i += stride) {
        int dst = (i < EE) ? ei[EE + i] : (i - EE);
        atomicAdd(&counts[dst], 1);
    }
}

// 1024 threads, 20 elements each, one hierarchical shfl scan
#define SCHUNK 20
__global__ __launch_bounds__(1024) void scan_kernel(const int* __restrict__ counts,
                                                    int* __restrict__ offsets,
                                                    int* __restrict__ cursor) {
    __shared__ int wsums[16];
    int t = threadIdx.x, lane = t & 63, wid = t >> 6;
    int base = t * SCHUNK;
    int loc[SCHUNK];
    int sum = 0;
    #pragma unroll
    for (int i = 0; i < SCHUNK; ++i) {
        int idx = base + i;
        int v = (idx < NN) ? counts[idx] : 0;
        loc[i] = sum; sum += v;
    }
    int x = sum;
    #pragma unroll
    for (int o = 1; o < 64; o <<= 1) { int tv = __shfl_up(x, o, 64); if (lane >= o) x += tv; }
    if (lane == 63) wsums[wid] = x;
    __syncthreads();
    if (wid == 0) {
        int wv = (lane < 16) ? wsums[lane] : 0;
        #pragma unroll
        for (int o = 1; o < 16; o <<= 1) { int tv = __shfl_up(wv, o, 64); if (lane >= o) wv += tv; }
        if (lane < 16) wsums[lane] = wv;   // inclusive wave sums
    }
    __syncthreads();
    int tbase = (wid ? wsums[wid - 1] : 0) + x - sum;   // exclusive thread base
    #pragma unroll
    for (int i = 0; i < SCHUNK; ++i) {
        int idx = base + i;
        if (idx < NN) { int e = tbase + loc[i]; offsets[idx] = e; cursor[idx] = e; }
    }
    if (t == 0) offsets[NN] = wsums[15];
}

__global__ void scatter_kernel(const int* __restrict__ ei, int* __restrict__ cursor,
                               int* __restrict__ csr_src) {
    int i = blockIdx.x * blockDim.x + threadIdx.x;
    int stride = gridDim.x * blockDim.x;
    for (; i < ETOT; i += stride) {
        int s, d;
        if (i < EE) { s = ei[i]; d = ei[EE + i]; }
        else        { s = i - EE; d = i - EE; }
        int pos = atomicAdd(&cursor[d], 1);
        csr_src[pos] = s;
    }
}

// ---------------------------------------------------------------------------
// Weight conversion (both layers): W[k][n] fp32 -> BhT/BlT [n][k] bf16 hi/lo
// ---------------------------------------------------------------------------
__global__ __launch_bounds__(256) void convB_kernel(const float* __restrict__ W1,
                                                    const float* __restrict__ W2,
                                                    short* __restrict__ BhT1,
                                                    short* __restrict__ BlT1,
                                                    short* __restrict__ BhT2,
                                                    short* __restrict__ BlT2) {
    int b = blockIdx.x;
    int n = b & 255, which = b >> 8;
    int k = threadIdx.x;
    const float* B = which ? W2 : W1;
    short* Bh = which ? BhT2 : BhT1;
    short* Bl = which ? BlT2 : BlT1;
    float x = B[k * DD + n];
    unsigned short hb = f2bf_hi(x);
    Bh[n * DD + k] = (short)hb;
    Bl[n * DD + k] = (short)f2bf_hi(x - bf2f(hb));
}

// ---------------------------------------------------------------------------
// MFMA GEMM: h = A[M x 256] @ W[256 x 256], split-bf16 3-pass.
// Outputs: hb (bf16 h) and PARTIAL dots asp/adp[colblock][row] (plain stores).
// ---------------------------------------------------------------------------
#define GBM 128
#define GBN 128
#define GBK 64

__global__ __launch_bounds__(256) void gemm_mfma_kernel(const float* __restrict__ A,
                                                        const short* __restrict__ BhT,
                                                        const short* __restrict__ BlT,
                                                        const float* __restrict__ a_src,
                                                        const float* __restrict__ a_dst,
                                                        short* __restrict__ hb,
                                                        float* __restrict__ asp,
                                                        float* __restrict__ adp,
                                                        int M) {
    __shared__ short As_h[GBM * GBK];
    __shared__ short As_l[GBM * GBK];
    __shared__ short Bs_h[GBN * GBK];
    __shared__ short Bs_l[GBN * GBK];
    int tid = threadIdx.x;
    int row0 = blockIdx.y * GBM;
    int col0 = blockIdx.x * GBN;
    int w = tid >> 6, lane = tid & 63;
    int wr = w >> 1, wc = w & 1;

    f32x4 acc[4][4];
    #pragma unroll
    for (int m = 0; m < 4; ++m)
        #pragma unroll
        for (int n = 0; n < 4; ++n)
            acc[m][n] = (f32x4){0.f, 0.f, 0.f, 0.f};

    int srow = tid >> 3;     // 0..31
    int sslot = tid & 7;     // 0..7

    for (int k0 = 0; k0 < DD; k0 += GBK) {
        __syncthreads();
        #pragma unroll
        for (int p = 0; p < 4; ++p) {
            int r = p * 32 + srow;
            int gr = row0 + r;
            float xv[8];
            if (gr < M) {
                const float4* ap = (const float4*)(A + (size_t)gr * DD + k0 + sslot * 8);
                float4 a0 = ap[0], a1 = ap[1];
                xv[0] = a0.x; xv[1] = a0.y; xv[2] = a0.z; xv[3] = a0.w;
                xv[4] = a1.x; xv[5] = a1.y; xv[6] = a1.z; xv[7] = a1.w;
            } else {
                #pragma unroll
                for (int i = 0; i < 8; ++i) xv[i] = 0.f;
            }
            s16x8 hv, lv;
            #pragma unroll
            for (int i = 0; i < 8; ++i) {
                unsigned short hbb = f2bf_hi(xv[i]);
                hv[i] = (short)hbb;
                lv[i] = (short)f2bf_hi(xv[i] - bf2f(hbb));
            }
            int byte = r * 128 + ((sslot ^ (r & 7)) << 4);
            *(s16x8*)((char*)As_h + byte) = hv;
            *(s16x8*)((char*)As_l + byte) = lv;
            const short* bhp = BhT + (size_t)(col0 + r) * DD + k0 + sslot * 8;
            const short* blp = BlT + (size_t)(col0 + r) * DD + k0 + sslot * 8;
            *(s16x8*)((char*)Bs_h + byte) = *(const s16x8*)bhp;
            *(s16x8*)((char*)Bs_l + byte) = *(const s16x8*)blp;
        }
        __syncthreads();

        #pragma unroll
        for (int ks = 0; ks < 2; ++ks) {
            s16x8 ah[4], al[4], bh[4], bl[4];
            int g = ks * 4 + (lane >> 4);
            #pragma unroll
            for (int m = 0; m < 4; ++m) {
                int r = wr * 64 + m * 16 + (lane & 15);
                int byte = r * 128 + ((g ^ (r & 7)) << 4);
                ah[m] = *(const s16x8*)((char*)As_h + byte);
                al[m] = *(const s16x8*)((char*)As_l + byte);
            }
            #pragma unroll
            for (int n = 0; n < 4; ++n) {
                int c = wc * 64 + n * 16 + (lane & 15);
                int byte = c * 128 + ((g ^ (c & 7)) << 4);
                bh[n] = *(const s16x8*)((char*)Bs_h + byte);
                bl[n] = *(const s16x8*)((char*)Bs_l + byte);
            }
            #pragma unroll
            for (int m = 0; m < 4; ++m)
                #pragma unroll
                for (int n = 0; n < 4; ++n) {
                    acc[m][n] = __builtin_amdgcn_mfma_f32_16x16x32_bf16(ah[m], bh[n], acc[m][n], 0, 0, 0);
                    acc[m][n] = __builtin_amdgcn_mfma_f32_16x16x32_bf16(ah[m], bl[n], acc[m][n], 0, 0, 0);
                    acc[m][n] = __builtin_amdgcn_mfma_f32_16x16x32_bf16(al[m], bh[n], acc[m][n], 0, 0, 0);
                }
        }
    }

    // ---- fused matvec partials (exact fp32 accumulators), plain stores ----
    float vsrc[4], vdst[4];
    #pragma unroll
    for (int n = 0; n < 4; ++n) {
        int cg = col0 + wc * 64 + n * 16 + (lane & 15);
        vsrc[n] = a_src[cg];
        vdst[n] = a_dst[cg];
    }
    #pragma unroll
    for (int m = 0; m < 4; ++m) {
        #pragma unroll
        for (int j = 0; j < 4; ++j) {
            float ps = 0.f, pd = 0.f;
            #pragma unroll
            for (int n = 0; n < 4; ++n) {
                float c = acc[m][n][j];
                ps += c * vsrc[n];
                pd += c * vdst[n];
            }
            #pragma unroll
            for (int o = 1; o < 16; o <<= 1) {
                ps += __shfl_xor(ps, o, 64);
                pd += __shfl_xor(pd, o, 64);
            }
            if ((lane & 15) == 0) {
                int rg = row0 + wr * 64 + m * 16 + ((lane >> 4) << 2) + j;
                if (rg < M) {
                    // wc=0 and wc=1 both produce partials for the SAME colblock
                    // (blockIdx.x); sum the two waves' halves via the n-loop above
                    // covering only this wave's 64 cols -> need cross-wave add:
                    // store per (colblock*2 + wc) would need 4 slots; instead
                    // atomic-free: accumulate the two wc halves via LDS? Simpler:
                    // asp is [2 colblocks][2 wc][N] -> flatten with blockIdx.x*2+wc
                    asp[(size_t)(blockIdx.x * 2 + wc) * NN + rg] = ps;
                    adp[(size_t)(blockIdx.x * 2 + wc) * NN + rg] = pd;
                }
            }
        }
    }

    // ---- bf16 h output ----
    #pragma unroll
    for (int m = 0; m < 4; ++m) {
        int rbase = row0 + wr * 64 + m * 16 + ((lane >> 4) << 2);
        #pragma unroll
        for (int n = 0; n < 4; ++n) {
            int cg = col0 + wc * 64 + n * 16 + (lane & 15);
            #pragma unroll
            for (int j = 0; j < 4; ++j) {
                int rg = rbase + j;
                if (rg < M) hb[(size_t)rg * DD + cg] = (short)f2bf_hi(acc[m][n][j]);
            }
        }
    }
}

// ---------------------------------------------------------------------------
// Alpha precompute: wave per node. Two passes over the node's CSR edges:
// (1) online max+sum of e = lrelu_0.2(as[src] + ad[n]); (2) write packed
// pairs {src, alpha}. as/ad summed from the 4 GEMM partial slabs.
// ---------------------------------------------------------------------------
__global__ __launch_bounds__(256) void alpha_kernel(const int* __restrict__ csr_src,
                                                    const int* __restrict__ offsets,
                                                    const float* __restrict__ asp,
                                                    const float* __restrict__ adp,
                                                    int2* __restrict__ pairs) {
    int tid = threadIdx.x;
    int w = tid >> 6, lane = tid & 63;
    int node = blockIdx.x * 4 + w;
    int off = offsets[node];
    int deg = offsets[node + 1] - off;
    float adn = adp[node] + adp[NN + node] + adp[2 * NN + node] + adp[3 * NN + node];
    float m = -INFINITY, s = 0.f;
    for (int cs = 0; cs < deg; cs += 64) {
        int cl = min(64, deg - cs);
        float e = -INFINITY;
        if (lane < cl) {
            int si = csr_src[off + cs + lane];
            float t = asp[si] + asp[NN + si] + asp[2 * NN + si] + asp[3 * NN + si] + adn;
            e = (t > 0.f) ? t : 0.2f * t;
        }
        float cm = e;
        #pragma unroll
        for (int o = 32; o > 0; o >>= 1) cm = fmaxf(cm, __shfl_xor(cm, o, 64));
        float newm = fmaxf(m, cm);
        float ex = (lane < cl) ? expf(e - newm) : 0.f;
        float csum = ex;
        #pragma unroll
        for (int o = 32; o > 0; o >>= 1) csum += __shfl_xor(csum, o, 64);
        s = s * expf(m - newm) + csum;
        m = newm;
    }
    float inv = 1.f / s;
    for (int cs = 0; cs < deg; cs += 64) {
        int cl = min(64, deg - cs);
        if (lane < cl) {
            int si = csr_src[off + cs + lane];
            float t = asp[si] + asp[NN + si] + asp[2 * NN + si] + asp[3 * NN + si] + adn;
            float e = (t > 0.f) ? t : 0.2f * t;
            int2 p;
            p.x = si;
            p.y = __float_as_int(expf(e - m) * inv);
            pairs[off + cs + lane] = p;
        }
    }
}

// ---------------------------------------------------------------------------
// Aggregation: wave per (node, 64-feature slice). Pure weighted gather:
// per edge: one wave-uniform 8B pair load (HW broadcast) + one coalesced
// 128B bf16 row-slice gather + fma. No shuffles, no LDS, no barriers.
// slice = blockIdx % 4 keeps each XCD's L2 pinned to one 2.5 MB h-slice.
// ---------------------------------------------------------------------------
__global__ __launch_bounds__(256) void aggregate_kernel(const short* __restrict__ hb,
                                                        const int2* __restrict__ pairs,
                                                        const int* __restrict__ offsets,
                                                        const float* __restrict__ bias,
                                                        float* __restrict__ out) {
    int tid = threadIdx.x;
    int w = tid >> 6, lane = tid & 63;
    int b = blockIdx.x;
    int sl = b & 3;
    int node = ((b >> 2) << 2) + w;
    int f = sl * 64 + lane;
    int off = offsets[node];
    int deg = offsets[node + 1] - off;
    const int2* pp = pairs + off;
    float acc = 0.f;
    int j = 0;
    for (; j + 4 <= deg; j += 4) {
        int2 p0 = pp[j], p1 = pp[j + 1], p2 = pp[j + 2], p3 = pp[j + 3];
        float h0 = bf2f((unsigned short)hb[p0.x * DD + f]);
        float h1 = bf2f((unsigned short)hb[p1.x * DD + f]);
        float h2 = bf2f((unsigned short)hb[p2.x * DD + f]);
        float h3 = bf2f((unsigned short)hb[p3.x * DD + f]);
        acc += __int_as_float(p0.y) * h0;
        acc += __int_as_float(p1.y) * h1;
        acc += __int_as_float(p2.y) * h2;
        acc += __int_as_float(p3.y) * h3;
    }
    for (; j < deg; ++j) {
        int2 p = pp[j];
        acc += __int_as_float(p.y) * bf2f((unsigned short)hb[p.x * DD + f]);
    }
    float r = acc + bias[f];
    r = (r > 0.f) ? r : 0.01f * r;
    __builtin_nontemporal_store(r, &out[(size_t)node * DD + f]);
}

// ---------------------------------------------------------------------------
// Pool: segment sums over sorted node ranges (BN folded into final)
// ---------------------------------------------------------------------------
#define PSLICE 8
__global__ __launch_bounds__(256) void pool_kernel(const float* __restrict__ h,
                                                   const int* __restrict__ start,
                                                   float* __restrict__ pool) {
    int g = blockIdx.x >> 3, sl = blockIdx.x & (PSLICE - 1);
    int f = threadIdx.x;
    int s0 = start[g], s1 = start[g + 1];
    float acc = 0.f;
    for (int nd = s0 + sl; nd < s1; nd += PSLICE)
        acc += h[(size_t)nd * DD + f];
    if (acc != 0.f || sl == 0) atomicAdd(&pool[g * DD + f], acc);
}

__global__ __launch_bounds__(256) void final_kernel(const float* __restrict__ pool,
                                                    const float* __restrict__ cnt,
                                                    const float* __restrict__ gam,
                                                    const float* __restrict__ bet,
                                                    const float* __restrict__ mean,
                                                    const float* __restrict__ var,
                                                    const float* __restrict__ Wl,
                                                    const float* __restrict__ bl,
                                                    float* __restrict__ out) {
    __shared__ float p_sh[DD];
    int g = blockIdx.x, j = threadIdx.x;
    float cn = cnt[g];
    float scale = gam[j] * rsqrtf(var[j] + BN_EPS);
    p_sh[j] = (cn > 0.f) ? (pool[g * DD + j] / cn - mean[j]) * scale + bet[j] : 0.f;
    __syncthreads();
    float acc = 0.f;
    for (int fi = 0; fi < DD; ++fi)
        acc += p_sh[fi] * Wl[j * DD + fi];
    out[g * DD + j] = acc + bl[j];
}

// ---------------------------------------------------------------------------
extern "C" void kernel_launch(void* const* d_in, const int* in_sizes, int n_in,
                              void* d_out, int out_size, void* d_ws, size_t ws_size,
                              hipStream_t stream) {
    const float* x       = (const float*)d_in[0];
    const int*   ei      = (const int*)d_in[1];
    const int*   batch   = (const int*)d_in[2];
    const float* W1      = (const float*)d_in[3];
    const float* a1_src  = (const float*)d_in[4];
    const float* a1_dst  = (const float*)d_in[5];
    const float* b1      = (const float*)d_in[6];
    const float* W2      = (const float*)d_in[7];
    const float* a2_src  = (const float*)d_in[8];
    const float* a2_dst  = (const float*)d_in[9];
    const float* b2      = (const float*)d_in[10];
    const float* bn_g    = (const float*)d_in[11];
    const float* bn_b    = (const float*)d_in[12];
    const float* bn_m    = (const float*)d_in[13];
    const float* bn_v    = (const float*)d_in[14];
    const float* Wl      = (const float*)d_in[15];
    const float* bl      = (const float*)d_in[16];
    float* out = (float*)d_out;

    char* ws = (char*)d_ws;
    size_t o = 0;
    auto take = [&](size_t bytes) { char* p = ws + o; o += (bytes + 255) & ~(size_t)255; return p; };
    int*   counts  = (int*)  take(NN * 4);
    int*   offsets = (int*)  take((NN + 1) * 4);
    int*   cursor  = (int*)  take(NN * 4);
    int*   csr_src = (int*)  take((size_t)ETOT * 4);
    int2*  pairs   = (int2*) take((size_t)ETOT * 8);
    float* asp     = (float*)take((size_t)4 * NN * 4);
    float* adp     = (float*)take((size_t)4 * NN * 4);
    short* hb      = (short*)take((size_t)NN * DD * 2);
    float* bufB    = (float*)take((size_t)NN * DD * 4);
    float* pool    = (float*)take(GG * DD * 4);
    float* cnt     = (float*)take(GG * 4);
    int*   start   = (int*)  take((GG + 1) * 4);
    short* BhT1    = (short*)take((size_t)DD * DD * 2);
    short* BlT1    = (short*)take((size_t)DD * DD * 2);
    short* BhT2    = (short*)take((size_t)DD * DD * 2);
    short* BlT2    = (short*)take((size_t)DD * DD * 2);
    (void)ws_size; (void)in_sizes; (void)n_in; (void)out_size;

    hipMemsetAsync(counts, 0, NN * 4, stream);
    hipMemsetAsync(pool, 0, GG * DD * 4, stream);

    // prep + CSR build
    prep_kernel<<<1, 128, 0, stream>>>(batch, start, cnt);
    hist_kernel<<<2579, 256, 0, stream>>>(ei, counts);
    scan_kernel<<<1, 1024, 0, stream>>>(counts, offsets, cursor);
    scatter_kernel<<<2579, 256, 0, stream>>>(ei, cursor, csr_src);

    // weight conversions (both layers, one launch)
    convB_kernel<<<2 * DD, 256, 0, stream>>>(W1, W2, BhT1, BlT1, BhT2, BlT2);

    dim3 ggrid(DD / GBN, (NN + GBM - 1) / GBM);

    // ---- layer 1 ----
    gemm_mfma_kernel<<<ggrid, 256, 0, stream>>>(x, BhT1, BlT1, a1_src, a1_dst, hb, asp, adp, NN);
    alpha_kernel<<<NN / 4, 256, 0, stream>>>(csr_src, offsets, asp, adp, pairs);
    aggregate_kernel<<<NN, 256, 0, stream>>>(hb, pairs, offsets, b1, bufB);

    // ---- layer 2 ----
    gemm_mfma_kernel<<<ggrid, 256, 0, stream>>>(bufB, BhT2, BlT2, a2_src, a2_dst, hb, asp, adp, NN);
    alpha_kernel<<<NN / 4, 256, 0, stream>>>(csr_src, offsets, asp, adp, pairs);
    aggregate_kernel<<<NN, 256, 0, stream>>>(hb, pairs, offsets, b2, bufB);

    // ---- pool + BN + linear ----
    pool_kernel<<<GG * PSLICE, 256, 0, stream>>>(bufB, start, pool);
    final_kernel<<<GG, 256, 0, stream>>>(pool, cnt, bn_g, bn_b, bn_m, bn_v, Wl, bl, out);
}

// Round 6
// 310.553 us; speedup vs baseline: 1.3299x; 1.2481x over previous
//
#include <hip/hip_runtime.h>
#include <hip/hip_bf16.h>

// Problem constants (match reference)
#define NN 20000
#define EE 640000
#define DD 256
#define GG 64
#define ETOT (EE + NN)   // edges + self loops = 660000
#define BN_EPS 1e-5f

typedef short s16x8 __attribute__((ext_vector_type(8)));
typedef short s16x4 __attribute__((ext_vector_type(4)));
typedef float f32x4 __attribute__((ext_vector_type(4)));

__device__ __forceinline__ unsigned short f2bf_hi(float x) {
    unsigned u = __float_as_uint(x);
    unsigned r = (u + 0x7FFFu + ((u >> 16) & 1u)) >> 16;   // RNE
    return (unsigned short)r;
}
__device__ __forceinline__ float bf2f(unsigned short h) {
    return __uint_as_float(((unsigned)h) << 16);
}

// ---------------------------------------------------------------------------
// Graph-boundary prep: batch is SORTED -> binary search, no atomics.
// ---------------------------------------------------------------------------
__global__ void prep_kernel(const int* __restrict__ batch, int* __restrict__ start,
                            float* __restrict__ cntf) {
    int g = threadIdx.x;
    if (g <= GG) {
        if (g == GG) start[GG] = NN;
        else {
            int lo = 0, hi = NN;
            while (lo < hi) { int mid = (lo + hi) >> 1; if (batch[mid] < g) lo = mid + 1; else hi = mid; }
            start[g] = lo;
        }
    }
    __syncthreads();
    if (g < GG) cntf[g] = (float)(start[g + 1] - start[g]);
}

// ---------------------------------------------------------------------------
// CSR build: histogram -> scan -> scatter (grouped by destination node)
// ---------------------------------------------------------------------------
__global__ void hist_kernel(const int* __restrict__ ei, int* __restrict__ counts) {
    int i = blockIdx.x * blockDim.x + threadIdx.x;
    int stride = gridDim.x * blockDim.x;
    for (; i < ETOT; i += stride) {
        int dst = (i < EE) ? ei[EE + i] : (i - EE);
        atomicAdd(&counts[dst], 1);
    }
}

// 1024 threads, 20 elements each, one hierarchical shfl scan
#define SCHUNK 20
__global__ __launch_bounds__(1024) void scan_kernel(const int* __restrict__ counts,
                                                    int* __restrict__ offsets,
                                                    int* __restrict__ cursor) {
    __shared__ int wsums[16];
    int t = threadIdx.x, lane = t & 63, wid = t >> 6;
    int base = t * SCHUNK;
    int loc[SCHUNK];
    int sum = 0;
    #pragma unroll
    for (int i = 0; i < SCHUNK; ++i) {
        int idx = base + i;
        int v = (idx < NN) ? counts[idx] : 0;
        loc[i] = sum; sum += v;
    }
    int x = sum;
    #pragma unroll
    for (int o = 1; o < 64; o <<= 1) { int tv = __shfl_up(x, o, 64); if (lane >= o) x += tv; }
    if (lane == 63) wsums[wid] = x;
    __syncthreads();
    if (wid == 0) {
        int wv = (lane < 16) ? wsums[lane] : 0;
        #pragma unroll
        for (int o = 1; o < 16; o <<= 1) { int tv = __shfl_up(wv, o, 64); if (lane >= o) wv += tv; }
        if (lane < 16) wsums[lane] = wv;   // inclusive wave sums
    }
    __syncthreads();
    int tbase = (wid ? wsums[wid - 1] : 0) + x - sum;   // exclusive thread base
    #pragma unroll
    for (int i = 0; i < SCHUNK; ++i) {
        int idx = base + i;
        if (idx < NN) { int e = tbase + loc[i]; offsets[idx] = e; cursor[idx] = e; }
    }
    if (t == 0) offsets[NN] = wsums[15];
}

__global__ void scatter_kernel(const int* __restrict__ ei, int* __restrict__ cursor,
                               int* __restrict__ csr_src) {
    int i = blockIdx.x * blockDim.x + threadIdx.x;
    int stride = gridDim.x * blockDim.x;
    for (; i < ETOT; i += stride) {
        int s, d;
        if (i < EE) { s = ei[i]; d = ei[EE + i]; }
        else        { s = i - EE; d = i - EE; }
        int pos = atomicAdd(&cursor[d], 1);
        csr_src[pos] = s;
    }
}

// ---------------------------------------------------------------------------
// Weight conversion (both layers): W[k][n] fp32 -> BhT/BlT [n][k] bf16 hi/lo
// ---------------------------------------------------------------------------
__global__ __launch_bounds__(256) void convB_kernel(const float* __restrict__ W1,
                                                    const float* __restrict__ W2,
                                                    short* __restrict__ BhT1,
                                                    short* __restrict__ BlT1,
                                                    short* __restrict__ BhT2,
                                                    short* __restrict__ BlT2) {
    int b = blockIdx.x;
    int n = b & 255, which = b >> 8;
    int k = threadIdx.x;
    const float* B = which ? W2 : W1;
    short* Bh = which ? BhT2 : BhT1;
    short* Bl = which ? BlT2 : BlT1;
    float x = B[k * DD + n];
    unsigned short hb = f2bf_hi(x);
    Bh[n * DD + k] = (short)hb;
    Bl[n * DD + k] = (short)f2bf_hi(x - bf2f(hb));
}

// ---------------------------------------------------------------------------
// MFMA GEMM: h = A[M x 256] @ W[256 x 256], split-bf16 3-pass.
// Outputs: hb (bf16 h) and PARTIAL dots asp/adp[colblock*2+wc][row].
// ---------------------------------------------------------------------------
#define GBM 128
#define GBN 128
#define GBK 64

__global__ __launch_bounds__(256) void gemm_mfma_kernel(const float* __restrict__ A,
                                                        const short* __restrict__ BhT,
                                                        const short* __restrict__ BlT,
                                                        const float* __restrict__ a_src,
                                                        const float* __restrict__ a_dst,
                                                        short* __restrict__ hb,
                                                        float* __restrict__ asp,
                                                        float* __restrict__ adp,
                                                        int M) {
    __shared__ short As_h[GBM * GBK];
    __shared__ short As_l[GBM * GBK];
    __shared__ short Bs_h[GBN * GBK];
    __shared__ short Bs_l[GBN * GBK];
    int tid = threadIdx.x;
    int row0 = blockIdx.y * GBM;
    int col0 = blockIdx.x * GBN;
    int w = tid >> 6, lane = tid & 63;
    int wr = w >> 1, wc = w & 1;

    f32x4 acc[4][4];
    #pragma unroll
    for (int m = 0; m < 4; ++m)
        #pragma unroll
        for (int n = 0; n < 4; ++n)
            acc[m][n] = (f32x4){0.f, 0.f, 0.f, 0.f};

    int srow = tid >> 3;     // 0..31
    int sslot = tid & 7;     // 0..7

    for (int k0 = 0; k0 < DD; k0 += GBK) {
        __syncthreads();
        #pragma unroll
        for (int p = 0; p < 4; ++p) {
            int r = p * 32 + srow;
            int gr = row0 + r;
            float xv[8];
            if (gr < M) {
                const float4* ap = (const float4*)(A + (size_t)gr * DD + k0 + sslot * 8);
                float4 a0 = ap[0], a1 = ap[1];
                xv[0] = a0.x; xv[1] = a0.y; xv[2] = a0.z; xv[3] = a0.w;
                xv[4] = a1.x; xv[5] = a1.y; xv[6] = a1.z; xv[7] = a1.w;
            } else {
                #pragma unroll
                for (int i = 0; i < 8; ++i) xv[i] = 0.f;
            }
            s16x8 hv, lv;
            #pragma unroll
            for (int i = 0; i < 8; ++i) {
                unsigned short hbb = f2bf_hi(xv[i]);
                hv[i] = (short)hbb;
                lv[i] = (short)f2bf_hi(xv[i] - bf2f(hbb));
            }
            int byte = r * 128 + ((sslot ^ (r & 7)) << 4);
            *(s16x8*)((char*)As_h + byte) = hv;
            *(s16x8*)((char*)As_l + byte) = lv;
            const short* bhp = BhT + (size_t)(col0 + r) * DD + k0 + sslot * 8;
            const short* blp = BlT + (size_t)(col0 + r) * DD + k0 + sslot * 8;
            *(s16x8*)((char*)Bs_h + byte) = *(const s16x8*)bhp;
            *(s16x8*)((char*)Bs_l + byte) = *(const s16x8*)blp;
        }
        __syncthreads();

        #pragma unroll
        for (int ks = 0; ks < 2; ++ks) {
            s16x8 ah[4], al[4], bh[4], bl[4];
            int g = ks * 4 + (lane >> 4);
            #pragma unroll
            for (int m = 0; m < 4; ++m) {
                int r = wr * 64 + m * 16 + (lane & 15);
                int byte = r * 128 + ((g ^ (r & 7)) << 4);
                ah[m] = *(const s16x8*)((char*)As_h + byte);
                al[m] = *(const s16x8*)((char*)As_l + byte);
            }
            #pragma unroll
            for (int n = 0; n < 4; ++n) {
                int c = wc * 64 + n * 16 + (lane & 15);
                int byte = c * 128 + ((g ^ (c & 7)) << 4);
                bh[n] = *(const s16x8*)((char*)Bs_h + byte);
                bl[n] = *(const s16x8*)((char*)Bs_l + byte);
            }
            #pragma unroll
            for (int m = 0; m < 4; ++m)
                #pragma unroll
                for (int n = 0; n < 4; ++n) {
                    acc[m][n] = __builtin_amdgcn_mfma_f32_16x16x32_bf16(ah[m], bh[n], acc[m][n], 0, 0, 0);
                    acc[m][n] = __builtin_amdgcn_mfma_f32_16x16x32_bf16(ah[m], bl[n], acc[m][n], 0, 0, 0);
                    acc[m][n] = __builtin_amdgcn_mfma_f32_16x16x32_bf16(al[m], bh[n], acc[m][n], 0, 0, 0);
                }
        }
    }

    // ---- fused matvec partials (exact fp32 accumulators), plain stores ----
    float vsrc[4], vdst[4];
    #pragma unroll
    for (int n = 0; n < 4; ++n) {
        int cg = col0 + wc * 64 + n * 16 + (lane & 15);
        vsrc[n] = a_src[cg];
        vdst[n] = a_dst[cg];
    }
    #pragma unroll
    for (int m = 0; m < 4; ++m) {
        #pragma unroll
        for (int j = 0; j < 4; ++j) {
            float ps = 0.f, pd = 0.f;
            #pragma unroll
            for (int n = 0; n < 4; ++n) {
                float c = acc[m][n][j];
                ps += c * vsrc[n];
                pd += c * vdst[n];
            }
            #pragma unroll
            for (int o = 1; o < 16; o <<= 1) {
                ps += __shfl_xor(ps, o, 64);
                pd += __shfl_xor(pd, o, 64);
            }
            if ((lane & 15) == 0) {
                int rg = row0 + wr * 64 + m * 16 + ((lane >> 4) << 2) + j;
                if (rg < M) {
                    asp[(size_t)(blockIdx.x * 2 + wc) * NN + rg] = ps;
                    adp[(size_t)(blockIdx.x * 2 + wc) * NN + rg] = pd;
                }
            }
        }
    }

    // ---- bf16 h output ----
    #pragma unroll
    for (int m = 0; m < 4; ++m) {
        int rbase = row0 + wr * 64 + m * 16 + ((lane >> 4) << 2);
        #pragma unroll
        for (int n = 0; n < 4; ++n) {
            int cg = col0 + wc * 64 + n * 16 + (lane & 15);
            #pragma unroll
            for (int j = 0; j < 4; ++j) {
                int rg = rbase + j;
                if (rg < M) hb[(size_t)rg * DD + cg] = (short)f2bf_hi(acc[m][n][j]);
            }
        }
    }
}

// ---------------------------------------------------------------------------
// Collapse the 4 GEMM partial slabs into as_/ad_ (one load chain per node)
// ---------------------------------------------------------------------------
__global__ void reduce_kernel(const float* __restrict__ asp, const float* __restrict__ adp,
                              float* __restrict__ as_, float* __restrict__ ad_) {
    int i = blockIdx.x * blockDim.x + threadIdx.x;
    if (i < NN) {
        as_[i] = asp[i] + asp[NN + i] + asp[2 * NN + i] + asp[3 * NN + i];
        ad_[i] = adp[i] + adp[NN + i] + adp[2 * NN + i] + adp[3 * NN + i];
    }
}

// ---------------------------------------------------------------------------
// Alpha precompute: wave per node. Fast path deg<=64 keeps e in registers
// (single pass); slow path does two passes. Writes packed {src, alpha}.
// ---------------------------------------------------------------------------
__global__ __launch_bounds__(256) void alpha_kernel(const int* __restrict__ csr_src,
                                                    const int* __restrict__ offsets,
                                                    const float* __restrict__ as_,
                                                    const float* __restrict__ ad_,
                                                    int2* __restrict__ pairs) {
    int tid = threadIdx.x;
    int w = tid >> 6, lane = tid & 63;
    int node = blockIdx.x * 4 + w;
    int off = offsets[node];
    int deg = offsets[node + 1] - off;
    float adn = ad_[node];

    if (deg <= 64) {
        int si = 0; float e = -INFINITY;
        if (lane < deg) {
            si = csr_src[off + lane];
            float t = as_[si] + adn;
            e = (t > 0.f) ? t : 0.2f * t;
        }
        float m = e;
        #pragma unroll
        for (int o = 32; o > 0; o >>= 1) m = fmaxf(m, __shfl_xor(m, o, 64));
        float ex = (lane < deg) ? expf(e - m) : 0.f;
        float s = ex;
        #pragma unroll
        for (int o = 32; o > 0; o >>= 1) s += __shfl_xor(s, o, 64);
        if (lane < deg) {
            int2 p; p.x = si; p.y = __float_as_int(ex / s);
            pairs[off + lane] = p;
        }
        return;
    }

    float m = -INFINITY, s = 0.f;
    for (int cs = 0; cs < deg; cs += 64) {
        int cl = min(64, deg - cs);
        float e = -INFINITY;
        if (lane < cl) {
            int si = csr_src[off + cs + lane];
            float t = as_[si] + adn;
            e = (t > 0.f) ? t : 0.2f * t;
        }
        float cm = e;
        #pragma unroll
        for (int o = 32; o > 0; o >>= 1) cm = fmaxf(cm, __shfl_xor(cm, o, 64));
        float newm = fmaxf(m, cm);
        float ex = (lane < cl) ? expf(e - newm) : 0.f;
        float csum = ex;
        #pragma unroll
        for (int o = 32; o > 0; o >>= 1) csum += __shfl_xor(csum, o, 64);
        s = s * expf(m - newm) + csum;
        m = newm;
    }
    float inv = 1.f / s;
    for (int cs = 0; cs < deg; cs += 64) {
        int cl = min(64, deg - cs);
        if (lane < cl) {
            int si = csr_src[off + cs + lane];
            float t = as_[si] + adn;
            float e = (t > 0.f) ? t : 0.2f * t;
            int2 p; p.x = si; p.y = __float_as_int(expf(e - m) * inv);
            pairs[off + cs + lane] = p;
        }
    }
}

// ---------------------------------------------------------------------------
// Aggregation v3: wave per (node, 64-feature slice). Lane split: 4 edge
// groups x 16 lanes; each lane loads 8B (4 bf16) of its edge's src row ->
// one wave-iter consumes 4 edges (128B/edge, coalesced per 16-lane group).
// Dual accumulators (8-edge unroll) keep loads in flight. slice=blockIdx%4
// keeps each XCD's L2 pinned to one 2.5MB h-slice. No LDS, no barriers;
// 8 one-time shfl_xor to merge edge groups.
// ---------------------------------------------------------------------------
__global__ __launch_bounds__(256) void aggregate_kernel(const short* __restrict__ hb,
                                                        const int2* __restrict__ pairs,
                                                        const int* __restrict__ offsets,
                                                        const float* __restrict__ bias,
                                                        float* __restrict__ out) {
    int tid = threadIdx.x;
    int w = tid >> 6, lane = tid & 63;
    int b = blockIdx.x;
    int sl = b & 3;
    int node = ((b >> 2) << 2) + w;
    int eg = lane >> 4;          // edge slot within quad
    int fl = lane & 15;          // feature quad within slice
    int f0 = sl * 64 + fl * 4;
    int off = offsets[node];
    int deg = offsets[node + 1] - off;
    const int2* pp = pairs + off;

    f32x4 acc0 = {0.f, 0.f, 0.f, 0.f}, acc1 = {0.f, 0.f, 0.f, 0.f};
    int j = 0;
    for (; j + 8 <= deg; j += 8) {
        int2 pA = pp[j + eg];
        int2 pB = pp[j + 4 + eg];
        s16x4 hA = *(const s16x4*)(hb + (size_t)pA.x * DD + f0);
        s16x4 hB = *(const s16x4*)(hb + (size_t)pB.x * DD + f0);
        float aA = __int_as_float(pA.y), aB = __int_as_float(pB.y);
        #pragma unroll
        for (int k = 0; k < 4; ++k) acc0[k] += aA * bf2f((unsigned short)hA[k]);
        #pragma unroll
        for (int k = 0; k < 4; ++k) acc1[k] += aB * bf2f((unsigned short)hB[k]);
    }
    {   // tail: up to 7 edges, two guarded quads
        int iA = j + eg, iB = j + 4 + eg;
        if (iA < deg) {
            int2 p = pp[iA];
            s16x4 hv = *(const s16x4*)(hb + (size_t)p.x * DD + f0);
            float a = __int_as_float(p.y);
            #pragma unroll
            for (int k = 0; k < 4; ++k) acc0[k] += a * bf2f((unsigned short)hv[k]);
        }
        if (iB < deg) {
            int2 p = pp[iB];
            s16x4 hv = *(const s16x4*)(hb + (size_t)p.x * DD + f0);
            float a = __int_as_float(p.y);
            #pragma unroll
            for (int k = 0; k < 4; ++k) acc1[k] += a * bf2f((unsigned short)hv[k]);
        }
    }
    // merge the 4 edge groups (features identical across groups)
    f32x4 r;
    #pragma unroll
    for (int k = 0; k < 4; ++k) {
        float v = acc0[k] + acc1[k];
        v += __shfl_xor(v, 16, 64);
        v += __shfl_xor(v, 32, 64);
        r[k] = v;
    }
    if (eg == 0) {
        const f32x4 bs = *(const f32x4*)(bias + f0);
        #pragma unroll
        for (int k = 0; k < 4; ++k) {
            float v = r[k] + bs[k];
            r[k] = (v > 0.f) ? v : 0.01f * v;
        }
        __builtin_nontemporal_store(r, (f32x4*)(out + (size_t)node * DD + f0));
    }
}

// ---------------------------------------------------------------------------
// Pool: segment sums over sorted node ranges (BN folded into final)
// ---------------------------------------------------------------------------
#define PSLICE 8
__global__ __launch_bounds__(256) void pool_kernel(const float* __restrict__ h,
                                                   const int* __restrict__ start,
                                                   float* __restrict__ pool) {
    int g = blockIdx.x >> 3, sl = blockIdx.x & (PSLICE - 1);
    int f = threadIdx.x;
    int s0 = start[g], s1 = start[g + 1];
    float acc = 0.f;
    for (int nd = s0 + sl; nd < s1; nd += PSLICE)
        acc += h[(size_t)nd * DD + f];
    if (acc != 0.f || sl == 0) atomicAdd(&pool[g * DD + f], acc);
}

__global__ __launch_bounds__(256) void final_kernel(const float* __restrict__ pool,
                                                    const float* __restrict__ cnt,
                                                    const float* __restrict__ gam,
                                                    const float* __restrict__ bet,
                                                    const float* __restrict__ mean,
                                                    const float* __restrict__ var,
                                                    const float* __restrict__ Wl,
                                                    const float* __restrict__ bl,
                                                    float* __restrict__ out) {
    __shared__ float p_sh[DD];
    int g = blockIdx.x, j = threadIdx.x;
    float cn = cnt[g];
    float scale = gam[j] * rsqrtf(var[j] + BN_EPS);
    p_sh[j] = (cn > 0.f) ? (pool[g * DD + j] / cn - mean[j]) * scale + bet[j] : 0.f;
    __syncthreads();
    float acc = 0.f;
    for (int fi = 0; fi < DD; ++fi)
        acc += p_sh[fi] * Wl[j * DD + fi];
    out[g * DD + j] = acc + bl[j];
}

// ---------------------------------------------------------------------------
extern "C" void kernel_launch(void* const* d_in, const int* in_sizes, int n_in,
                              void* d_out, int out_size, void* d_ws, size_t ws_size,
                              hipStream_t stream) {
    const float* x       = (const float*)d_in[0];
    const int*   ei      = (const int*)d_in[1];
    const int*   batch   = (const int*)d_in[2];
    const float* W1      = (const float*)d_in[3];
    const float* a1_src  = (const float*)d_in[4];
    const float* a1_dst  = (const float*)d_in[5];
    const float* b1      = (const float*)d_in[6];
    const float* W2      = (const float*)d_in[7];
    const float* a2_src  = (const float*)d_in[8];
    const float* a2_dst  = (const float*)d_in[9];
    const float* b2      = (const float*)d_in[10];
    const float* bn_g    = (const float*)d_in[11];
    const float* bn_b    = (const float*)d_in[12];
    const float* bn_m    = (const float*)d_in[13];
    const float* bn_v    = (const float*)d_in[14];
    const float* Wl      = (const float*)d_in[15];
    const float* bl      = (const float*)d_in[16];
    float* out = (float*)d_out;

    char* ws = (char*)d_ws;
    size_t o = 0;
    auto take = [&](size_t bytes) { char* p = ws + o; o += (bytes + 255) & ~(size_t)255; return p; };
    int*   counts  = (int*)  take(NN * 4);
    int*   offsets = (int*)  take((NN + 1) * 4);
    int*   cursor  = (int*)  take(NN * 4);
    int*   csr_src = (int*)  take((size_t)ETOT * 4);
    int2*  pairs   = (int2*) take((size_t)ETOT * 8);
    float* asp     = (float*)take((size_t)4 * NN * 4);
    float* adp     = (float*)take((size_t)4 * NN * 4);
    float* as_     = (float*)take(NN * 4);
    float* ad_     = (float*)take(NN * 4);
    short* hb      = (short*)take((size_t)NN * DD * 2);
    float* bufB    = (float*)take((size_t)NN * DD * 4);
    float* pool    = (float*)take(GG * DD * 4);
    float* cnt     = (float*)take(GG * 4);
    int*   start   = (int*)  take((GG + 1) * 4);
    short* BhT1    = (short*)take((size_t)DD * DD * 2);
    short* BlT1    = (short*)take((size_t)DD * DD * 2);
    short* BhT2    = (short*)take((size_t)DD * DD * 2);
    short* BlT2    = (short*)take((size_t)DD * DD * 2);
    (void)ws_size; (void)in_sizes; (void)n_in; (void)out_size;

    hipMemsetAsync(counts, 0, NN * 4, stream);
    hipMemsetAsync(pool, 0, GG * DD * 4, stream);

    // prep + CSR build
    prep_kernel<<<1, 128, 0, stream>>>(batch, start, cnt);
    hist_kernel<<<2579, 256, 0, stream>>>(ei, counts);
    scan_kernel<<<1, 1024, 0, stream>>>(counts, offsets, cursor);
    scatter_kernel<<<2579, 256, 0, stream>>>(ei, cursor, csr_src);

    // weight conversions (both layers, one launch)
    convB_kernel<<<2 * DD, 256, 0, stream>>>(W1, W2, BhT1, BlT1, BhT2, BlT2);

    dim3 ggrid(DD / GBN, (NN + GBM - 1) / GBM);

    // ---- layer 1 ----
    gemm_mfma_kernel<<<ggrid, 256, 0, stream>>>(x, BhT1, BlT1, a1_src, a1_dst, hb, asp, adp, NN);
    reduce_kernel<<<(NN + 255) / 256, 256, 0, stream>>>(asp, adp, as_, ad_);
    alpha_kernel<<<NN / 4, 256, 0, stream>>>(csr_src, offsets, as_, ad_, pairs);
    aggregate_kernel<<<NN, 256, 0, stream>>>(hb, pairs, offsets, b1, bufB);

    // ---- layer 2 ----
    gemm_mfma_kernel<<<ggrid, 256, 0, stream>>>(bufB, BhT2, BlT2, a2_src, a2_dst, hb, asp, adp, NN);
    reduce_kernel<<<(NN + 255) / 256, 256, 0, stream>>>(asp, adp, as_, ad_);
    alpha_kernel<<<NN / 4, 256, 0, stream>>>(csr_src, offsets, as_, ad_, pairs);
    aggregate_kernel<<<NN, 256, 0, stream>>>(hb, pairs, offsets, b2, bufB);

    // ---- pool + BN + linear ----
    pool_kernel<<<GG * PSLICE, 256, 0, stream>>>(bufB, start, pool);
    final_kernel<<<GG, 256, 0, stream>>>(pool, cnt, bn_g, bn_b, bn_m, bn_v, Wl, bl, out);
}

// Round 7
// 289.245 us; speedup vs baseline: 1.4279x; 1.0737x over previous
//
#include <hip/hip_runtime.h>
#include <hip/hip_bf16.h>

// Problem constants (match reference)
#define NN 20000
#define EE 640000
#define DD 256
#define GG 64
#define ETOT (EE + NN)   // edges + self loops = 660000
#define BN_EPS 1e-5f

typedef short s16x8 __attribute__((ext_vector_type(8)));
typedef short s16x4 __attribute__((ext_vector_type(4)));
typedef float f32x4 __attribute__((ext_vector_type(4)));
typedef int   i32x2 __attribute__((ext_vector_type(2)));

__device__ __forceinline__ unsigned short f2bf_hi(float x) {
    unsigned u = __float_as_uint(x);
    unsigned r = (u + 0x7FFFu + ((u >> 16) & 1u)) >> 16;   // RNE
    return (unsigned short)r;
}
__device__ __forceinline__ float bf2f(unsigned short h) {
    return __uint_as_float(((unsigned)h) << 16);
}

// ---------------------------------------------------------------------------
// Graph-boundary prep: batch is SORTED -> binary search, no atomics.
// ---------------------------------------------------------------------------
__global__ void prep_kernel(const int* __restrict__ batch, int* __restrict__ start,
                            float* __restrict__ cntf) {
    int g = threadIdx.x;
    if (g <= GG) {
        if (g == GG) start[GG] = NN;
        else {
            int lo = 0, hi = NN;
            while (lo < hi) { int mid = (lo + hi) >> 1; if (batch[mid] < g) lo = mid + 1; else hi = mid; }
            start[g] = lo;
        }
    }
    __syncthreads();
    if (g < GG) cntf[g] = (float)(start[g + 1] - start[g]);
}

// ---------------------------------------------------------------------------
// CSR build: histogram -> scan -> scatter (grouped by destination node)
// ---------------------------------------------------------------------------
__global__ void hist_kernel(const int* __restrict__ ei, int* __restrict__ counts) {
    int i = blockIdx.x * blockDim.x + threadIdx.x;
    int stride = gridDim.x * blockDim.x;
    for (; i < ETOT; i += stride) {
        int dst = (i < EE) ? ei[EE + i] : (i - EE);
        atomicAdd(&counts[dst], 1);
    }
}

// 1024 threads, 20 elements each, one hierarchical shfl scan
#define SCHUNK 20
__global__ __launch_bounds__(1024) void scan_kernel(const int* __restrict__ counts,
                                                    int* __restrict__ offsets,
                                                    int* __restrict__ cursor) {
    __shared__ int wsums[16];
    int t = threadIdx.x, lane = t & 63, wid = t >> 6;
    int base = t * SCHUNK;
    int loc[SCHUNK];
    int sum = 0;
    #pragma unroll
    for (int i = 0; i < SCHUNK; ++i) {
        int idx = base + i;
        int v = (idx < NN) ? counts[idx] : 0;
        loc[i] = sum; sum += v;
    }
    int x = sum;
    #pragma unroll
    for (int o = 1; o < 64; o <<= 1) { int tv = __shfl_up(x, o, 64); if (lane >= o) x += tv; }
    if (lane == 63) wsums[wid] = x;
    __syncthreads();
    if (wid == 0) {
        int wv = (lane < 16) ? wsums[lane] : 0;
        #pragma unroll
        for (int o = 1; o < 16; o <<= 1) { int tv = __shfl_up(wv, o, 64); if (lane >= o) wv += tv; }
        if (lane < 16) wsums[lane] = wv;   // inclusive wave sums
    }
    __syncthreads();
    int tbase = (wid ? wsums[wid - 1] : 0) + x - sum;   // exclusive thread base
    #pragma unroll
    for (int i = 0; i < SCHUNK; ++i) {
        int idx = base + i;
        if (idx < NN) { int e = tbase + loc[i]; offsets[idx] = e; cursor[idx] = e; }
    }
    if (t == 0) offsets[NN] = wsums[15];
}

__global__ void scatter_kernel(const int* __restrict__ ei, int* __restrict__ cursor,
                               int* __restrict__ csr_src) {
    int i = blockIdx.x * blockDim.x + threadIdx.x;
    int stride = gridDim.x * blockDim.x;
    for (; i < ETOT; i += stride) {
        int s, d;
        if (i < EE) { s = ei[i]; d = ei[EE + i]; }
        else        { s = i - EE; d = i - EE; }
        int pos = atomicAdd(&cursor[d], 1);
        csr_src[pos] = s;
    }
}

// ---------------------------------------------------------------------------
// Weight conversion (both layers): W[k][n] fp32 -> BhT/BlT [n][k] bf16 hi/lo
// ---------------------------------------------------------------------------
__global__ __launch_bounds__(256) void convB_kernel(const float* __restrict__ W1,
                                                    const float* __restrict__ W2,
                                                    short* __restrict__ BhT1,
                                                    short* __restrict__ BlT1,
                                                    short* __restrict__ BhT2,
                                                    short* __restrict__ BlT2) {
    int b = blockIdx.x;
    int n = b & 255, which = b >> 8;
    int k = threadIdx.x;
    const float* B = which ? W2 : W1;
    short* Bh = which ? BhT2 : BhT1;
    short* Bl = which ? BlT2 : BlT1;
    float x = B[k * DD + n];
    unsigned short hb = f2bf_hi(x);
    Bh[n * DD + k] = (short)hb;
    Bl[n * DD + k] = (short)f2bf_hi(x - bf2f(hb));
}

// ---------------------------------------------------------------------------
// MFMA GEMM: h = A[M x 256] @ W[256 x 256], split-bf16 3-pass.
// Outputs: hb (bf16 h) and PARTIAL dots asp/adp[colblock*2+wc][row].
// ---------------------------------------------------------------------------
#define GBM 128
#define GBN 128
#define GBK 64

__global__ __launch_bounds__(256) void gemm_mfma_kernel(const float* __restrict__ A,
                                                        const short* __restrict__ BhT,
                                                        const short* __restrict__ BlT,
                                                        const float* __restrict__ a_src,
                                                        const float* __restrict__ a_dst,
                                                        short* __restrict__ hb,
                                                        float* __restrict__ asp,
                                                        float* __restrict__ adp,
                                                        int M) {
    __shared__ short As_h[GBM * GBK];
    __shared__ short As_l[GBM * GBK];
    __shared__ short Bs_h[GBN * GBK];
    __shared__ short Bs_l[GBN * GBK];
    int tid = threadIdx.x;
    int row0 = blockIdx.y * GBM;
    int col0 = blockIdx.x * GBN;
    int w = tid >> 6, lane = tid & 63;
    int wr = w >> 1, wc = w & 1;

    f32x4 acc[4][4];
    #pragma unroll
    for (int m = 0; m < 4; ++m)
        #pragma unroll
        for (int n = 0; n < 4; ++n)
            acc[m][n] = (f32x4){0.f, 0.f, 0.f, 0.f};

    int srow = tid >> 3;     // 0..31
    int sslot = tid & 7;     // 0..7

    for (int k0 = 0; k0 < DD; k0 += GBK) {
        __syncthreads();
        #pragma unroll
        for (int p = 0; p < 4; ++p) {
            int r = p * 32 + srow;
            int gr = row0 + r;
            float xv[8];
            if (gr < M) {
                const float4* ap = (const float4*)(A + (size_t)gr * DD + k0 + sslot * 8);
                float4 a0 = ap[0], a1 = ap[1];
                xv[0] = a0.x; xv[1] = a0.y; xv[2] = a0.z; xv[3] = a0.w;
                xv[4] = a1.x; xv[5] = a1.y; xv[6] = a1.z; xv[7] = a1.w;
            } else {
                #pragma unroll
                for (int i = 0; i < 8; ++i) xv[i] = 0.f;
            }
            s16x8 hv, lv;
            #pragma unroll
            for (int i = 0; i < 8; ++i) {
                unsigned short hbb = f2bf_hi(xv[i]);
                hv[i] = (short)hbb;
                lv[i] = (short)f2bf_hi(xv[i] - bf2f(hbb));
            }
            int byte = r * 128 + ((sslot ^ (r & 7)) << 4);
            *(s16x8*)((char*)As_h + byte) = hv;
            *(s16x8*)((char*)As_l + byte) = lv;
            const short* bhp = BhT + (size_t)(col0 + r) * DD + k0 + sslot * 8;
            const short* blp = BlT + (size_t)(col0 + r) * DD + k0 + sslot * 8;
            *(s16x8*)((char*)Bs_h + byte) = *(const s16x8*)bhp;
            *(s16x8*)((char*)Bs_l + byte) = *(const s16x8*)blp;
        }
        __syncthreads();

        #pragma unroll
        for (int ks = 0; ks < 2; ++ks) {
            s16x8 ah[4], al[4], bh[4], bl[4];
            int g = ks * 4 + (lane >> 4);
            #pragma unroll
            for (int m = 0; m < 4; ++m) {
                int r = wr * 64 + m * 16 + (lane & 15);
                int byte = r * 128 + ((g ^ (r & 7)) << 4);
                ah[m] = *(const s16x8*)((char*)As_h + byte);
                al[m] = *(const s16x8*)((char*)As_l + byte);
            }
            #pragma unroll
            for (int n = 0; n < 4; ++n) {
                int c = wc * 64 + n * 16 + (lane & 15);
                int byte = c * 128 + ((g ^ (c & 7)) << 4);
                bh[n] = *(const s16x8*)((char*)Bs_h + byte);
                bl[n] = *(const s16x8*)((char*)Bs_l + byte);
            }
            #pragma unroll
            for (int m = 0; m < 4; ++m)
                #pragma unroll
                for (int n = 0; n < 4; ++n) {
                    acc[m][n] = __builtin_amdgcn_mfma_f32_16x16x32_bf16(ah[m], bh[n], acc[m][n], 0, 0, 0);
                    acc[m][n] = __builtin_amdgcn_mfma_f32_16x16x32_bf16(ah[m], bl[n], acc[m][n], 0, 0, 0);
                    acc[m][n] = __builtin_amdgcn_mfma_f32_16x16x32_bf16(al[m], bh[n], acc[m][n], 0, 0, 0);
                }
        }
    }

    // ---- fused matvec partials (exact fp32 accumulators), plain stores ----
    float vsrc[4], vdst[4];
    #pragma unroll
    for (int n = 0; n < 4; ++n) {
        int cg = col0 + wc * 64 + n * 16 + (lane & 15);
        vsrc[n] = a_src[cg];
        vdst[n] = a_dst[cg];
    }
    #pragma unroll
    for (int m = 0; m < 4; ++m) {
        #pragma unroll
        for (int j = 0; j < 4; ++j) {
            float ps = 0.f, pd = 0.f;
            #pragma unroll
            for (int n = 0; n < 4; ++n) {
                float c = acc[m][n][j];
                ps += c * vsrc[n];
                pd += c * vdst[n];
            }
            #pragma unroll
            for (int o = 1; o < 16; o <<= 1) {
                ps += __shfl_xor(ps, o, 64);
                pd += __shfl_xor(pd, o, 64);
            }
            if ((lane & 15) == 0) {
                int rg = row0 + wr * 64 + m * 16 + ((lane >> 4) << 2) + j;
                if (rg < M) {
                    asp[(size_t)(blockIdx.x * 2 + wc) * NN + rg] = ps;
                    adp[(size_t)(blockIdx.x * 2 + wc) * NN + rg] = pd;
                }
            }
        }
    }

    // ---- bf16 h output ----
    #pragma unroll
    for (int m = 0; m < 4; ++m) {
        int rbase = row0 + wr * 64 + m * 16 + ((lane >> 4) << 2);
        #pragma unroll
        for (int n = 0; n < 4; ++n) {
            int cg = col0 + wc * 64 + n * 16 + (lane & 15);
            #pragma unroll
            for (int j = 0; j < 4; ++j) {
                int rg = rbase + j;
                if (rg < M) hb[(size_t)rg * DD + cg] = (short)f2bf_hi(acc[m][n][j]);
            }
        }
    }
}

// ---------------------------------------------------------------------------
// Collapse the 4 GEMM partial slabs into as_/ad_ (one load chain per node)
// ---------------------------------------------------------------------------
__global__ void reduce_kernel(const float* __restrict__ asp, const float* __restrict__ adp,
                              float* __restrict__ as_, float* __restrict__ ad_) {
    int i = blockIdx.x * blockDim.x + threadIdx.x;
    if (i < NN) {
        as_[i] = asp[i] + asp[NN + i] + asp[2 * NN + i] + asp[3 * NN + i];
        ad_[i] = adp[i] + adp[NN + i] + adp[2 * NN + i] + adp[3 * NN + i];
    }
}

// ---------------------------------------------------------------------------
// Alpha precompute: wave per node. Fast path deg<=64 keeps e in registers
// (single pass); slow path does two passes. Writes packed {src, alpha}.
// ---------------------------------------------------------------------------
__global__ __launch_bounds__(256) void alpha_kernel(const int* __restrict__ csr_src,
                                                    const int* __restrict__ offsets,
                                                    const float* __restrict__ as_,
                                                    const float* __restrict__ ad_,
                                                    int2* __restrict__ pairs) {
    int tid = threadIdx.x;
    int w = tid >> 6, lane = tid & 63;
    int node = blockIdx.x * 4 + w;
    int off = offsets[node];
    int deg = offsets[node + 1] - off;
    float adn = ad_[node];

    if (deg <= 64) {
        int si = 0; float e = -INFINITY;
        if (lane < deg) {
            si = csr_src[off + lane];
            float t = as_[si] + adn;
            e = (t > 0.f) ? t : 0.2f * t;
        }
        float m = e;
        #pragma unroll
        for (int o = 32; o > 0; o >>= 1) m = fmaxf(m, __shfl_xor(m, o, 64));
        float ex = (lane < deg) ? expf(e - m) : 0.f;
        float s = ex;
        #pragma unroll
        for (int o = 32; o > 0; o >>= 1) s += __shfl_xor(s, o, 64);
        if (lane < deg) {
            int2 p; p.x = si; p.y = __float_as_int(ex / s);
            pairs[off + lane] = p;
        }
        return;
    }

    float m = -INFINITY, s = 0.f;
    for (int cs = 0; cs < deg; cs += 64) {
        int cl = min(64, deg - cs);
        float e = -INFINITY;
        if (lane < cl) {
            int si = csr_src[off + cs + lane];
            float t = as_[si] + adn;
            e = (t > 0.f) ? t : 0.2f * t;
        }
        float cm = e;
        #pragma unroll
        for (int o = 32; o > 0; o >>= 1) cm = fmaxf(cm, __shfl_xor(cm, o, 64));
        float newm = fmaxf(m, cm);
        float ex = (lane < cl) ? expf(e - newm) : 0.f;
        float csum = ex;
        #pragma unroll
        for (int o = 32; o > 0; o >>= 1) csum += __shfl_xor(csum, o, 64);
        s = s * expf(m - newm) + csum;
        m = newm;
    }
    float inv = 1.f / s;
    for (int cs = 0; cs < deg; cs += 64) {
        int cl = min(64, deg - cs);
        if (lane < cl) {
            int si = csr_src[off + cs + lane];
            float t = as_[si] + adn;
            float e = (t > 0.f) ? t : 0.2f * t;
            int2 p; p.x = si; p.y = __float_as_int(expf(e - m) * inv);
            pairs[off + cs + lane] = p;
        }
    }
}

// ---------------------------------------------------------------------------
// Aggregation v4: wave per (node, 64-feature slice). Lane split: 8 edge
// groups x 8 lanes; each lane loads 16B (8 bf16) of its edge's src row ->
// one gather instr moves 8 edges x 128B = 1KB. 16 edges/iter, 2 chains,
// pairs PREFETCHED one iteration ahead (software pipeline) so the only
// exposed latency is the gather itself. slice=blockIdx%4 pins each XCD's
// L2 to one 2.5MB h-slice. No LDS, no barriers; 24 shfl_xor once at end.
// ---------------------------------------------------------------------------
__global__ __launch_bounds__(256) void aggregate_kernel(const short* __restrict__ hb,
                                                        const int2* __restrict__ pairs,
                                                        const int* __restrict__ offsets,
                                                        const float* __restrict__ bias,
                                                        float* __restrict__ out) {
    int tid = threadIdx.x;
    int w = tid >> 6, lane = tid & 63;
    int b = blockIdx.x;
    int sl = b & 3;
    int node = ((b >> 2) << 2) + w;
    int eg = lane >> 3;          // edge slot within 8-group
    int fl = lane & 7;           // feature octet
    int f0 = sl * 64 + fl * 8;
    int off = offsets[node];
    int deg = offsets[node + 1] - off;
    const i32x2* pp = (const i32x2*)pairs + off;

    float accA[8], accB[8];
    #pragma unroll
    for (int k = 0; k < 8; ++k) { accA[k] = 0.f; accB[k] = 0.f; }

    int j = 0;
    i32x2 qA, qB;
    if (deg >= 16) { qA = pp[eg]; qB = pp[8 + eg]; }
    for (; j + 32 <= deg; j += 16) {
        i32x2 nA = pp[j + 16 + eg];                  // prefetch next iter
        i32x2 nB = pp[j + 24 + eg];
        s16x8 hA = *(const s16x8*)(hb + (size_t)qA.x * DD + f0);
        s16x8 hB = *(const s16x8*)(hb + (size_t)qB.x * DD + f0);
        float aA = __int_as_float(qA.y), aB = __int_as_float(qB.y);
        #pragma unroll
        for (int k = 0; k < 8; ++k) accA[k] += aA * bf2f((unsigned short)hA[k]);
        #pragma unroll
        for (int k = 0; k < 8; ++k) accB[k] += aB * bf2f((unsigned short)hB[k]);
        qA = nA; qB = nB;
    }
    if (j + 16 <= deg) {                             // last full iter (pairs in regs)
        s16x8 hA = *(const s16x8*)(hb + (size_t)qA.x * DD + f0);
        s16x8 hB = *(const s16x8*)(hb + (size_t)qB.x * DD + f0);
        float aA = __int_as_float(qA.y), aB = __int_as_float(qB.y);
        #pragma unroll
        for (int k = 0; k < 8; ++k) accA[k] += aA * bf2f((unsigned short)hA[k]);
        #pragma unroll
        for (int k = 0; k < 8; ++k) accB[k] += aB * bf2f((unsigned short)hB[k]);
        j += 16;
    }
    {   // tail: up to 15 edges, two guarded per-group singles
        if (j + eg < deg) {
            i32x2 p = pp[j + eg];
            s16x8 hv = *(const s16x8*)(hb + (size_t)p.x * DD + f0);
            float a = __int_as_float(p.y);
            #pragma unroll
            for (int k = 0; k < 8; ++k) accA[k] += a * bf2f((unsigned short)hv[k]);
        }
        if (j + 8 + eg < deg) {
            i32x2 p = pp[j + 8 + eg];
            s16x8 hv = *(const s16x8*)(hb + (size_t)p.x * DD + f0);
            float a = __int_as_float(p.y);
            #pragma unroll
            for (int k = 0; k < 8; ++k) accB[k] += a * bf2f((unsigned short)hv[k]);
        }
    }

    // merge the 8 edge groups (feature octets identical across groups)
    f32x4 r0, r1;
    #pragma unroll
    for (int k = 0; k < 8; ++k) {
        float v = accA[k] + accB[k];
        v += __shfl_xor(v, 8, 64);
        v += __shfl_xor(v, 16, 64);
        v += __shfl_xor(v, 32, 64);
        if (k < 4) r0[k] = v; else r1[k - 4] = v;
    }
    if (eg == 0) {
        const f32x4 b0 = *(const f32x4*)(bias + f0);
        const f32x4 b1 = *(const f32x4*)(bias + f0 + 4);
        #pragma unroll
        for (int k = 0; k < 4; ++k) {
            float v0 = r0[k] + b0[k];
            float v1 = r1[k] + b1[k];
            r0[k] = (v0 > 0.f) ? v0 : 0.01f * v0;
            r1[k] = (v1 > 0.f) ? v1 : 0.01f * v1;
        }
        __builtin_nontemporal_store(r0, (f32x4*)(out + (size_t)node * DD + f0));
        __builtin_nontemporal_store(r1, (f32x4*)(out + (size_t)node * DD + f0 + 4));
    }
}

// ---------------------------------------------------------------------------
// Pool: segment sums over sorted node ranges (BN folded into final)
// ---------------------------------------------------------------------------
#define PSLICE 8
__global__ __launch_bounds__(256) void pool_kernel(const float* __restrict__ h,
                                                   const int* __restrict__ start,
                                                   float* __restrict__ pool) {
    int g = blockIdx.x >> 3, sl = blockIdx.x & (PSLICE - 1);
    int f = threadIdx.x;
    int s0 = start[g], s1 = start[g + 1];
    float acc = 0.f;
    for (int nd = s0 + sl; nd < s1; nd += PSLICE)
        acc += h[(size_t)nd * DD + f];
    if (acc != 0.f || sl == 0) atomicAdd(&pool[g * DD + f], acc);
}

__global__ __launch_bounds__(256) void final_kernel(const float* __restrict__ pool,
                                                    const float* __restrict__ cnt,
                                                    const float* __restrict__ gam,
                                                    const float* __restrict__ bet,
                                                    const float* __restrict__ mean,
                                                    const float* __restrict__ var,
                                                    const float* __restrict__ Wl,
                                                    const float* __restrict__ bl,
                                                    float* __restrict__ out) {
    __shared__ float p_sh[DD];
    int g = blockIdx.x, j = threadIdx.x;
    float cn = cnt[g];
    float scale = gam[j] * rsqrtf(var[j] + BN_EPS);
    p_sh[j] = (cn > 0.f) ? (pool[g * DD + j] / cn - mean[j]) * scale + bet[j] : 0.f;
    __syncthreads();
    float acc = 0.f;
    for (int fi = 0; fi < DD; ++fi)
        acc += p_sh[fi] * Wl[j * DD + fi];
    out[g * DD + j] = acc + bl[j];
}

// ---------------------------------------------------------------------------
extern "C" void kernel_launch(void* const* d_in, const int* in_sizes, int n_in,
                              void* d_out, int out_size, void* d_ws, size_t ws_size,
                              hipStream_t stream) {
    const float* x       = (const float*)d_in[0];
    const int*   ei      = (const int*)d_in[1];
    const int*   batch   = (const int*)d_in[2];
    const float* W1      = (const float*)d_in[3];
    const float* a1_src  = (const float*)d_in[4];
    const float* a1_dst  = (const float*)d_in[5];
    const float* b1      = (const float*)d_in[6];
    const float* W2      = (const float*)d_in[7];
    const float* a2_src  = (const float*)d_in[8];
    const float* a2_dst  = (const float*)d_in[9];
    const float* b2      = (const float*)d_in[10];
    const float* bn_g    = (const float*)d_in[11];
    const float* bn_b    = (const float*)d_in[12];
    const float* bn_m    = (const float*)d_in[13];
    const float* bn_v    = (const float*)d_in[14];
    const float* Wl      = (const float*)d_in[15];
    const float* bl      = (const float*)d_in[16];
    float* out = (float*)d_out;

    char* ws = (char*)d_ws;
    size_t o = 0;
    auto take = [&](size_t bytes) { char* p = ws + o; o += (bytes + 255) & ~(size_t)255; return p; };
    int*   counts  = (int*)  take(NN * 4);
    int*   offsets = (int*)  take((NN + 1) * 4);
    int*   cursor  = (int*)  take(NN * 4);
    int*   csr_src = (int*)  take((size_t)ETOT * 4);
    int2*  pairs   = (int2*) take((size_t)ETOT * 8);
    float* asp     = (float*)take((size_t)4 * NN * 4);
    float* adp     = (float*)take((size_t)4 * NN * 4);
    float* as_     = (float*)take(NN * 4);
    float* ad_     = (float*)take(NN * 4);
    short* hb      = (short*)take((size_t)NN * DD * 2);
    float* bufB    = (float*)take((size_t)NN * DD * 4);
    float* pool    = (float*)take(GG * DD * 4);
    float* cnt     = (float*)take(GG * 4);
    int*   start   = (int*)  take((GG + 1) * 4);
    short* BhT1    = (short*)take((size_t)DD * DD * 2);
    short* BlT1    = (short*)take((size_t)DD * DD * 2);
    short* BhT2    = (short*)take((size_t)DD * DD * 2);
    short* BlT2    = (short*)take((size_t)DD * DD * 2);
    (void)ws_size; (void)in_sizes; (void)n_in; (void)out_size;

    hipMemsetAsync(counts, 0, NN * 4, stream);
    hipMemsetAsync(pool, 0, GG * DD * 4, stream);

    // prep + CSR build
    prep_kernel<<<1, 128, 0, stream>>>(batch, start, cnt);
    hist_kernel<<<2579, 256, 0, stream>>>(ei, counts);
    scan_kernel<<<1, 1024, 0, stream>>>(counts, offsets, cursor);
    scatter_kernel<<<2579, 256, 0, stream>>>(ei, cursor, csr_src);

    // weight conversions (both layers, one launch)
    convB_kernel<<<2 * DD, 256, 0, stream>>>(W1, W2, BhT1, BlT1, BhT2, BlT2);

    dim3 ggrid(DD / GBN, (NN + GBM - 1) / GBM);

    // ---- layer 1 ----
    gemm_mfma_kernel<<<ggrid, 256, 0, stream>>>(x, BhT1, BlT1, a1_src, a1_dst, hb, asp, adp, NN);
    reduce_kernel<<<(NN + 255) / 256, 256, 0, stream>>>(asp, adp, as_, ad_);
    alpha_kernel<<<NN / 4, 256, 0, stream>>>(csr_src, offsets, as_, ad_, pairs);
    aggregate_kernel<<<NN, 256, 0, stream>>>(hb, pairs, offsets, b1, bufB);

    // ---- layer 2 ----
    gemm_mfma_kernel<<<ggrid, 256, 0, stream>>>(bufB, BhT2, BlT2, a2_src, a2_dst, hb, asp, adp, NN);
    reduce_kernel<<<(NN + 255) / 256, 256, 0, stream>>>(asp, adp, as_, ad_);
    alpha_kernel<<<NN / 4, 256, 0, stream>>>(csr_src, offsets, as_, ad_, pairs);
    aggregate_kernel<<<NN, 256, 0, stream>>>(hb, pairs, offsets, b2, bufB);

    // ---- pool + BN + linear ----
    pool_kernel<<<GG * PSLICE, 256, 0, stream>>>(bufB, start, pool);
    final_kernel<<<GG, 256, 0, stream>>>(pool, cnt, bn_g, bn_b, bn_m, bn_v, Wl, bl, out);
}

// Round 8
// 271.073 us; speedup vs baseline: 1.5236x; 1.0670x over previous
//
#include <hip/hip_runtime.h>
#include <hip/hip_bf16.h>

// Problem constants (match reference)
#define NN 20000
#define EE 640000
#define DD 256
#define GG 64
#define ETOT (EE + NN)   // edges + self loops = 660000
#define BN_EPS 1e-5f

typedef short s16x8 __attribute__((ext_vector_type(8)));
typedef float f32x4 __attribute__((ext_vector_type(4)));
typedef int   i32x2 __attribute__((ext_vector_type(2)));

__device__ __forceinline__ unsigned short f2bf_hi(float x) {
    unsigned u = __float_as_uint(x);
    unsigned r = (u + 0x7FFFu + ((u >> 16) & 1u)) >> 16;   // RNE
    return (unsigned short)r;
}
__device__ __forceinline__ float bf2f(unsigned short h) {
    return __uint_as_float(((unsigned)h) << 16);
}

// ---------------------------------------------------------------------------
// Graph-boundary prep: batch is SORTED -> binary search, no atomics.
// ---------------------------------------------------------------------------
__global__ void prep_kernel(const int* __restrict__ batch, int* __restrict__ start,
                            float* __restrict__ cntf) {
    int g = threadIdx.x;
    if (g <= GG) {
        if (g == GG) start[GG] = NN;
        else {
            int lo = 0, hi = NN;
            while (lo < hi) { int mid = (lo + hi) >> 1; if (batch[mid] < g) lo = mid + 1; else hi = mid; }
            start[g] = lo;
        }
    }
    __syncthreads();
    if (g < GG) cntf[g] = (float)(start[g + 1] - start[g]);
}

// ---------------------------------------------------------------------------
// CSR build over the EE real edges only (self-loops handled analytically:
// scan adds +1 per node; reduce_kernel writes the self-loop into the
// bucket's reserved last slot). Batched x4 for atomic ILP.
// ---------------------------------------------------------------------------
#define HS_BLOCKS 640           // 640*256*4 = 655360 >= EE
__global__ __launch_bounds__(256) void hist_kernel(const int* __restrict__ ei,
                                                   int* __restrict__ counts) {
    int t = blockIdx.x * 256 + threadIdx.x;
    const int T = HS_BLOCKS * 256;
    int d[4];
    #pragma unroll
    for (int k = 0; k < 4; ++k) {
        int i = t + k * T;
        d[k] = (i < EE) ? ei[EE + i] : -1;
    }
    #pragma unroll
    for (int k = 0; k < 4; ++k)
        if (d[k] >= 0) atomicAdd(&counts[d[k]], 1);
}

// 1024 threads, 20 elements each, one hierarchical shfl scan.
// v = counts + 1 (the +1 is each node's self-loop).
#define SCHUNK 20
__global__ __launch_bounds__(1024) void scan_kernel(const int* __restrict__ counts,
                                                    int* __restrict__ offsets,
                                                    int* __restrict__ cursor) {
    __shared__ int wsums[16];
    int t = threadIdx.x, lane = t & 63, wid = t >> 6;
    int base = t * SCHUNK;
    int loc[SCHUNK];
    int sum = 0;
    #pragma unroll
    for (int i = 0; i < SCHUNK; ++i) {
        int idx = base + i;
        int v = (idx < NN) ? (counts[idx] + 1) : 0;
        loc[i] = sum; sum += v;
    }
    int x = sum;
    #pragma unroll
    for (int o = 1; o < 64; o <<= 1) { int tv = __shfl_up(x, o, 64); if (lane >= o) x += tv; }
    if (lane == 63) wsums[wid] = x;
    __syncthreads();
    if (wid == 0) {
        int wv = (lane < 16) ? wsums[lane] : 0;
        #pragma unroll
        for (int o = 1; o < 16; o <<= 1) { int tv = __shfl_up(wv, o, 64); if (lane >= o) wv += tv; }
        if (lane < 16) wsums[lane] = wv;   // inclusive wave sums
    }
    __syncthreads();
    int tbase = (wid ? wsums[wid - 1] : 0) + x - sum;   // exclusive thread base
    #pragma unroll
    for (int i = 0; i < SCHUNK; ++i) {
        int idx = base + i;
        if (idx < NN) { int e = tbase + loc[i]; offsets[idx] = e; cursor[idx] = e; }
    }
    if (t == 0) offsets[NN] = wsums[15];
}

__global__ __launch_bounds__(256) void scatter_kernel(const int* __restrict__ ei,
                                                      int* __restrict__ cursor,
                                                      int* __restrict__ csr_src) {
    int t = blockIdx.x * 256 + threadIdx.x;
    const int T = HS_BLOCKS * 256;
    int s[4], d[4], pos[4];
    #pragma unroll
    for (int k = 0; k < 4; ++k) {
        int i = t + k * T;
        bool v = (i < EE);
        s[k] = v ? ei[i] : 0;
        d[k] = v ? ei[EE + i] : -1;
    }
    #pragma unroll
    for (int k = 0; k < 4; ++k)
        if (d[k] >= 0) pos[k] = atomicAdd(&cursor[d[k]], 1);
    #pragma unroll
    for (int k = 0; k < 4; ++k)
        if (d[k] >= 0) csr_src[pos[k]] = s[k];
}

// ---------------------------------------------------------------------------
// Weight conversion (both layers): W[k][n] fp32 -> BhT/BlT [n][k] bf16 hi/lo
// ---------------------------------------------------------------------------
__global__ __launch_bounds__(256) void convB_kernel(const float* __restrict__ W1,
                                                    const float* __restrict__ W2,
                                                    short* __restrict__ BhT1,
                                                    short* __restrict__ BlT1,
                                                    short* __restrict__ BhT2,
                                                    short* __restrict__ BlT2) {
    int b = blockIdx.x;
    int n = b & 255, which = b >> 8;
    int k = threadIdx.x;
    const float* B = which ? W2 : W1;
    short* Bh = which ? BhT2 : BhT1;
    short* Bl = which ? BlT2 : BlT1;
    float x = B[k * DD + n];
    unsigned short hb = f2bf_hi(x);
    Bh[n * DD + k] = (short)hb;
    Bl[n * DD + k] = (short)f2bf_hi(x - bf2f(hb));
}

// ---------------------------------------------------------------------------
// MFMA GEMM: h = A[M x 256] @ W[256 x 256], split-bf16 3-pass.
// GBM=64 (626 blocks -> ~1.25-round makespan, 3 blocks/CU at 48KB LDS).
// Outputs: hb (bf16 h) and PARTIAL dots asp/adp[colblock*2+wc][row].
// ---------------------------------------------------------------------------
#define GBM 64
#define GBN 128
#define GBK 64

__global__ __launch_bounds__(256) void gemm_mfma_kernel(const float* __restrict__ A,
                                                        const short* __restrict__ BhT,
                                                        const short* __restrict__ BlT,
                                                        const float* __restrict__ a_src,
                                                        const float* __restrict__ a_dst,
                                                        short* __restrict__ hb,
                                                        float* __restrict__ asp,
                                                        float* __restrict__ adp,
                                                        int M) {
    __shared__ short As_h[GBM * GBK];
    __shared__ short As_l[GBM * GBK];
    __shared__ short Bs_h[GBN * GBK];
    __shared__ short Bs_l[GBN * GBK];
    int tid = threadIdx.x;
    int row0 = blockIdx.y * GBM;
    int col0 = blockIdx.x * GBN;
    int w = tid >> 6, lane = tid & 63;
    int wr = w >> 1, wc = w & 1;   // wr: 32-row half, wc: 64-col half

    f32x4 acc[2][4];
    #pragma unroll
    for (int m = 0; m < 2; ++m)
        #pragma unroll
        for (int n = 0; n < 4; ++n)
            acc[m][n] = (f32x4){0.f, 0.f, 0.f, 0.f};

    int srow = tid >> 3;     // 0..31
    int sslot = tid & 7;     // 0..7

    for (int k0 = 0; k0 < DD; k0 += GBK) {
        __syncthreads();
        // ---- A tile: 64 rows, fp32 -> bf16 hi/lo on the fly ----
        #pragma unroll
        for (int p = 0; p < 2; ++p) {
            int r = p * 32 + srow;
            int gr = row0 + r;
            float xv[8];
            if (gr < M) {
                const float4* ap = (const float4*)(A + (size_t)gr * DD + k0 + sslot * 8);
                float4 a0 = ap[0], a1 = ap[1];
                xv[0] = a0.x; xv[1] = a0.y; xv[2] = a0.z; xv[3] = a0.w;
                xv[4] = a1.x; xv[5] = a1.y; xv[6] = a1.z; xv[7] = a1.w;
            } else {
                #pragma unroll
                for (int i = 0; i < 8; ++i) xv[i] = 0.f;
            }
            s16x8 hv, lv;
            #pragma unroll
            for (int i = 0; i < 8; ++i) {
                unsigned short hbb = f2bf_hi(xv[i]);
                hv[i] = (short)hbb;
                lv[i] = (short)f2bf_hi(xv[i] - bf2f(hbb));
            }
            int byte = r * 128 + ((sslot ^ (r & 7)) << 4);
            *(s16x8*)((char*)As_h + byte) = hv;
            *(s16x8*)((char*)As_l + byte) = lv;
        }
        // ---- B tiles: 128 n-rows, pre-converted bf16 ----
        #pragma unroll
        for (int p = 0; p < 4; ++p) {
            int r = p * 32 + srow;
            int byte = r * 128 + ((sslot ^ (r & 7)) << 4);
            const short* bhp = BhT + (size_t)(col0 + r) * DD + k0 + sslot * 8;
            const short* blp = BlT + (size_t)(col0 + r) * DD + k0 + sslot * 8;
            *(s16x8*)((char*)Bs_h + byte) = *(const s16x8*)bhp;
            *(s16x8*)((char*)Bs_l + byte) = *(const s16x8*)blp;
        }
        __syncthreads();

        #pragma unroll
        for (int ks = 0; ks < 2; ++ks) {
            s16x8 ah[2], al[2], bh[4], bl[4];
            int g = ks * 4 + (lane >> 4);
            #pragma unroll
            for (int m = 0; m < 2; ++m) {
                int r = wr * 32 + m * 16 + (lane & 15);
                int byte = r * 128 + ((g ^ (r & 7)) << 4);
                ah[m] = *(const s16x8*)((char*)As_h + byte);
                al[m] = *(const s16x8*)((char*)As_l + byte);
            }
            #pragma unroll
            for (int n = 0; n < 4; ++n) {
                int c = wc * 64 + n * 16 + (lane & 15);
                int byte = c * 128 + ((g ^ (c & 7)) << 4);
                bh[n] = *(const s16x8*)((char*)Bs_h + byte);
                bl[n] = *(const s16x8*)((char*)Bs_l + byte);
            }
            #pragma unroll
            for (int m = 0; m < 2; ++m)
                #pragma unroll
                for (int n = 0; n < 4; ++n) {
                    acc[m][n] = __builtin_amdgcn_mfma_f32_16x16x32_bf16(ah[m], bh[n], acc[m][n], 0, 0, 0);
                    acc[m][n] = __builtin_amdgcn_mfma_f32_16x16x32_bf16(ah[m], bl[n], acc[m][n], 0, 0, 0);
                    acc[m][n] = __builtin_amdgcn_mfma_f32_16x16x32_bf16(al[m], bh[n], acc[m][n], 0, 0, 0);
                }
        }
    }

    // ---- fused matvec partials (exact fp32 accumulators), plain stores ----
    float vsrc[4], vdst[4];
    #pragma unroll
    for (int n = 0; n < 4; ++n) {
        int cg = col0 + wc * 64 + n * 16 + (lane & 15);
        vsrc[n] = a_src[cg];
        vdst[n] = a_dst[cg];
    }
    #pragma unroll
    for (int m = 0; m < 2; ++m) {
        #pragma unroll
        for (int j = 0; j < 4; ++j) {
            float ps = 0.f, pd = 0.f;
            #pragma unroll
            for (int n = 0; n < 4; ++n) {
                float c = acc[m][n][j];
                ps += c * vsrc[n];
                pd += c * vdst[n];
            }
            #pragma unroll
            for (int o = 1; o < 16; o <<= 1) {
                ps += __shfl_xor(ps, o, 64);
                pd += __shfl_xor(pd, o, 64);
            }
            if ((lane & 15) == 0) {
                int rg = row0 + wr * 32 + m * 16 + ((lane >> 4) << 2) + j;
                if (rg < M) {
                    asp[(size_t)(blockIdx.x * 2 + wc) * NN + rg] = ps;
                    adp[(size_t)(blockIdx.x * 2 + wc) * NN + rg] = pd;
                }
            }
        }
    }

    // ---- bf16 h output ----
    #pragma unroll
    for (int m = 0; m < 2; ++m) {
        int rbase = row0 + wr * 32 + m * 16 + ((lane >> 4) << 2);
        #pragma unroll
        for (int n = 0; n < 4; ++n) {
            int cg = col0 + wc * 64 + n * 16 + (lane & 15);
            #pragma unroll
            for (int j = 0; j < 4; ++j) {
                int rg = rbase + j;
                if (rg < M) hb[(size_t)rg * DD + cg] = (short)f2bf_hi(acc[m][n][j]);
            }
        }
    }
}

// ---------------------------------------------------------------------------
// Collapse the 4 GEMM partial slabs into as_/ad_; also drop each node's
// self-loop into the reserved LAST slot of its CSR bucket.
// ---------------------------------------------------------------------------
__global__ void reduce_kernel(const float* __restrict__ asp, const float* __restrict__ adp,
                              const int* __restrict__ offsets,
                              float* __restrict__ as_, float* __restrict__ ad_,
                              int* __restrict__ csr_src) {
    int i = blockIdx.x * blockDim.x + threadIdx.x;
    if (i < NN) {
        as_[i] = asp[i] + asp[NN + i] + asp[2 * NN + i] + asp[3 * NN + i];
        ad_[i] = adp[i] + adp[NN + i] + adp[2 * NN + i] + adp[3 * NN + i];
        csr_src[offsets[i + 1] - 1] = i;   // self-loop
    }
}

// ---------------------------------------------------------------------------
// Alpha precompute: wave per node. Fast path deg<=64 keeps e in registers
// (single pass); slow path does two passes. Writes packed {src, alpha}.
// ---------------------------------------------------------------------------
__global__ __launch_bounds__(256) void alpha_kernel(const int* __restrict__ csr_src,
                                                    const int* __restrict__ offsets,
                                                    const float* __restrict__ as_,
                                                    const float* __restrict__ ad_,
                                                    int2* __restrict__ pairs) {
    int tid = threadIdx.x;
    int w = tid >> 6, lane = tid & 63;
    int node = blockIdx.x * 4 + w;
    int off = offsets[node];
    int deg = offsets[node + 1] - off;
    float adn = ad_[node];

    if (deg <= 64) {
        int si = 0; float e = -INFINITY;
        if (lane < deg) {
            si = csr_src[off + lane];
            float t = as_[si] + adn;
            e = (t > 0.f) ? t : 0.2f * t;
        }
        float m = e;
        #pragma unroll
        for (int o = 32; o > 0; o >>= 1) m = fmaxf(m, __shfl_xor(m, o, 64));
        float ex = (lane < deg) ? expf(e - m) : 0.f;
        float s = ex;
        #pragma unroll
        for (int o = 32; o > 0; o >>= 1) s += __shfl_xor(s, o, 64);
        if (lane < deg) {
            int2 p; p.x = si; p.y = __float_as_int(ex / s);
            pairs[off + lane] = p;
        }
        return;
    }

    float m = -INFINITY, s = 0.f;
    for (int cs = 0; cs < deg; cs += 64) {
        int cl = min(64, deg - cs);
        float e = -INFINITY;
        if (lane < cl) {
            int si = csr_src[off + cs + lane];
            float t = as_[si] + adn;
            e = (t > 0.f) ? t : 0.2f * t;
        }
        float cm = e;
        #pragma unroll
        for (int o = 32; o > 0; o >>= 1) cm = fmaxf(cm, __shfl_xor(cm, o, 64));
        float newm = fmaxf(m, cm);
        float ex = (lane < cl) ? expf(e - newm) : 0.f;
        float csum = ex;
        #pragma unroll
        for (int o = 32; o > 0; o >>= 1) csum += __shfl_xor(csum, o, 64);
        s = s * expf(m - newm) + csum;
        m = newm;
    }
    float inv = 1.f / s;
    for (int cs = 0; cs < deg; cs += 64) {
        int cl = min(64, deg - cs);
        if (lane < cl) {
            int si = csr_src[off + cs + lane];
            float t = as_[si] + adn;
            float e = (t > 0.f) ? t : 0.2f * t;
            int2 p; p.x = si; p.y = __float_as_int(expf(e - m) * inv);
            pairs[off + cs + lane] = p;
        }
    }
}

// ---------------------------------------------------------------------------
// Aggregation v4: wave per (node, 64-feature slice). 8 edge groups x 8
// lanes x 16B loads; pairs prefetched one iteration ahead. slice=blockIdx%4
// pins each XCD's L2 to one 2.5MB h-slice.
// ---------------------------------------------------------------------------
__global__ __launch_bounds__(256) void aggregate_kernel(const short* __restrict__ hb,
                                                        const int2* __restrict__ pairs,
                                                        const int* __restrict__ offsets,
                                                        const float* __restrict__ bias,
                                                        float* __restrict__ out) {
    int tid = threadIdx.x;
    int w = tid >> 6, lane = tid & 63;
    int b = blockIdx.x;
    int sl = b & 3;
    int node = ((b >> 2) << 2) + w;
    int eg = lane >> 3;          // edge slot within 8-group
    int fl = lane & 7;           // feature octet
    int f0 = sl * 64 + fl * 8;
    int off = offsets[node];
    int deg = offsets[node + 1] - off;
    const i32x2* pp = (const i32x2*)pairs + off;

    float accA[8], accB[8];
    #pragma unroll
    for (int k = 0; k < 8; ++k) { accA[k] = 0.f; accB[k] = 0.f; }

    int j = 0;
    i32x2 qA, qB;
    if (deg >= 16) { qA = pp[eg]; qB = pp[8 + eg]; }
    for (; j + 32 <= deg; j += 16) {
        i32x2 nA = pp[j + 16 + eg];                  // prefetch next iter
        i32x2 nB = pp[j + 24 + eg];
        s16x8 hA = *(const s16x8*)(hb + (size_t)qA.x * DD + f0);
        s16x8 hB = *(const s16x8*)(hb + (size_t)qB.x * DD + f0);
        float aA = __int_as_float(qA.y), aB = __int_as_float(qB.y);
        #pragma unroll
        for (int k = 0; k < 8; ++k) accA[k] += aA * bf2f((unsigned short)hA[k]);
        #pragma unroll
        for (int k = 0; k < 8; ++k) accB[k] += aB * bf2f((unsigned short)hB[k]);
        qA = nA; qB = nB;
    }
    if (j + 16 <= deg) {                             // last full iter (pairs in regs)
        s16x8 hA = *(const s16x8*)(hb + (size_t)qA.x * DD + f0);
        s16x8 hB = *(const s16x8*)(hb + (size_t)qB.x * DD + f0);
        float aA = __int_as_float(qA.y), aB = __int_as_float(qB.y);
        #pragma unroll
        for (int k = 0; k < 8; ++k) accA[k] += aA * bf2f((unsigned short)hA[k]);
        #pragma unroll
        for (int k = 0; k < 8; ++k) accB[k] += aB * bf2f((unsigned short)hB[k]);
        j += 16;
    }
    {   // tail: up to 15 edges, two guarded per-group singles
        if (j + eg < deg) {
            i32x2 p = pp[j + eg];
            s16x8 hv = *(const s16x8*)(hb + (size_t)p.x * DD + f0);
            float a = __int_as_float(p.y);
            #pragma unroll
            for (int k = 0; k < 8; ++k) accA[k] += a * bf2f((unsigned short)hv[k]);
        }
        if (j + 8 + eg < deg) {
            i32x2 p = pp[j + 8 + eg];
            s16x8 hv = *(const s16x8*)(hb + (size_t)p.x * DD + f0);
            float a = __int_as_float(p.y);
            #pragma unroll
            for (int k = 0; k < 8; ++k) accB[k] += a * bf2f((unsigned short)hv[k]);
        }
    }

    // merge the 8 edge groups (feature octets identical across groups)
    f32x4 r0, r1;
    #pragma unroll
    for (int k = 0; k < 8; ++k) {
        float v = accA[k] + accB[k];
        v += __shfl_xor(v, 8, 64);
        v += __shfl_xor(v, 16, 64);
        v += __shfl_xor(v, 32, 64);
        if (k < 4) r0[k] = v; else r1[k - 4] = v;
    }
    if (eg == 0) {
        const f32x4 b0 = *(const f32x4*)(bias + f0);
        const f32x4 b1 = *(const f32x4*)(bias + f0 + 4);
        #pragma unroll
        for (int k = 0; k < 4; ++k) {
            float v0 = r0[k] + b0[k];
            float v1 = r1[k] + b1[k];
            r0[k] = (v0 > 0.f) ? v0 : 0.01f * v0;
            r1[k] = (v1 > 0.f) ? v1 : 0.01f * v1;
        }
        __builtin_nontemporal_store(r0, (f32x4*)(out + (size_t)node * DD + f0));
        __builtin_nontemporal_store(r1, (f32x4*)(out + (size_t)node * DD + f0 + 4));
    }
}

// ---------------------------------------------------------------------------
// Pool: segment sums over sorted node ranges (BN folded into final)
// ---------------------------------------------------------------------------
#define PSLICE 8
__global__ __launch_bounds__(256) void pool_kernel(const float* __restrict__ h,
                                                   const int* __restrict__ start,
                                                   float* __restrict__ pool) {
    int g = blockIdx.x >> 3, sl = blockIdx.x & (PSLICE - 1);
    int f = threadIdx.x;
    int s0 = start[g], s1 = start[g + 1];
    float acc = 0.f;
    for (int nd = s0 + sl; nd < s1; nd += PSLICE)
        acc += h[(size_t)nd * DD + f];
    if (acc != 0.f || sl == 0) atomicAdd(&pool[g * DD + f], acc);
}

__global__ __launch_bounds__(256) void final_kernel(const float* __restrict__ pool,
                                                    const float* __restrict__ cnt,
                                                    const float* __restrict__ gam,
                                                    const float* __restrict__ bet,
                                                    const float* __restrict__ mean,
                                                    const float* __restrict__ var,
                                                    const float* __restrict__ Wl,
                                                    const float* __restrict__ bl,
                                                    float* __restrict__ out) {
    __shared__ float p_sh[DD];
    int g = blockIdx.x, j = threadIdx.x;
    float cn = cnt[g];
    float scale = gam[j] * rsqrtf(var[j] + BN_EPS);
    p_sh[j] = (cn > 0.f) ? (pool[g * DD + j] / cn - mean[j]) * scale + bet[j] : 0.f;
    __syncthreads();
    float acc = 0.f;
    for (int fi = 0; fi < DD; ++fi)
        acc += p_sh[fi] * Wl[j * DD + fi];
    out[g * DD + j] = acc + bl[j];
}

// ---------------------------------------------------------------------------
extern "C" void kernel_launch(void* const* d_in, const int* in_sizes, int n_in,
                              void* d_out, int out_size, void* d_ws, size_t ws_size,
                              hipStream_t stream) {
    const float* x       = (const float*)d_in[0];
    const int*   ei      = (const int*)d_in[1];
    const int*   batch   = (const int*)d_in[2];
    const float* W1      = (const float*)d_in[3];
    const float* a1_src  = (const float*)d_in[4];
    const float* a1_dst  = (const float*)d_in[5];
    const float* b1      = (const float*)d_in[6];
    const float* W2      = (const float*)d_in[7];
    const float* a2_src  = (const float*)d_in[8];
    const float* a2_dst  = (const float*)d_in[9];
    const float* b2      = (const float*)d_in[10];
    const float* bn_g    = (const float*)d_in[11];
    const float* bn_b    = (const float*)d_in[12];
    const float* bn_m    = (const float*)d_in[13];
    const float* bn_v    = (const float*)d_in[14];
    const float* Wl      = (const float*)d_in[15];
    const float* bl      = (const float*)d_in[16];
    float* out = (float*)d_out;

    char* ws = (char*)d_ws;
    size_t o = 0;
    auto take = [&](size_t bytes) { char* p = ws + o; o += (bytes + 255) & ~(size_t)255; return p; };
    int*   counts  = (int*)  take(NN * 4);
    int*   offsets = (int*)  take((NN + 1) * 4);
    int*   cursor  = (int*)  take(NN * 4);
    int*   csr_src = (int*)  take((size_t)ETOT * 4);
    int2*  pairs   = (int2*) take((size_t)ETOT * 8);
    float* asp     = (float*)take((size_t)4 * NN * 4);
    float* adp     = (float*)take((size_t)4 * NN * 4);
    float* as_     = (float*)take(NN * 4);
    float* ad_     = (float*)take(NN * 4);
    short* hb      = (short*)take((size_t)NN * DD * 2);
    float* bufB    = (float*)take((size_t)NN * DD * 4);
    float* pool    = (float*)take(GG * DD * 4);
    float* cnt     = (float*)take(GG * 4);
    int*   start   = (int*)  take((GG + 1) * 4);
    short* BhT1    = (short*)take((size_t)DD * DD * 2);
    short* BlT1    = (short*)take((size_t)DD * DD * 2);
    short* BhT2    = (short*)take((size_t)DD * DD * 2);
    short* BlT2    = (short*)take((size_t)DD * DD * 2);
    (void)ws_size; (void)in_sizes; (void)n_in; (void)out_size;

    hipMemsetAsync(counts, 0, NN * 4, stream);
    hipMemsetAsync(pool, 0, GG * DD * 4, stream);

    // prep + CSR build (EE real edges; self-loops analytic)
    prep_kernel<<<1, 128, 0, stream>>>(batch, start, cnt);
    hist_kernel<<<HS_BLOCKS, 256, 0, stream>>>(ei, counts);
    scan_kernel<<<1, 1024, 0, stream>>>(counts, offsets, cursor);
    scatter_kernel<<<HS_BLOCKS, 256, 0, stream>>>(ei, cursor, csr_src);

    // weight conversions (both layers, one launch)
    convB_kernel<<<2 * DD, 256, 0, stream>>>(W1, W2, BhT1, BlT1, BhT2, BlT2);

    dim3 ggrid(DD / GBN, (NN + GBM - 1) / GBM);

    // ---- layer 1 ----
    gemm_mfma_kernel<<<ggrid, 256, 0, stream>>>(x, BhT1, BlT1, a1_src, a1_dst, hb, asp, adp, NN);
    reduce_kernel<<<(NN + 255) / 256, 256, 0, stream>>>(asp, adp, offsets, as_, ad_, csr_src);
    alpha_kernel<<<NN / 4, 256, 0, stream>>>(csr_src, offsets, as_, ad_, pairs);
    aggregate_kernel<<<NN, 256, 0, stream>>>(hb, pairs, offsets, b1, bufB);

    // ---- layer 2 ----
    gemm_mfma_kernel<<<ggrid, 256, 0, stream>>>(bufB, BhT2, BlT2, a2_src, a2_dst, hb, asp, adp, NN);
    reduce_kernel<<<(NN + 255) / 256, 256, 0, stream>>>(asp, adp, offsets, as_, ad_, csr_src);
    alpha_kernel<<<NN / 4, 256, 0, stream>>>(csr_src, offsets, as_, ad_, pairs);
    aggregate_kernel<<<NN, 256, 0, stream>>>(hb, pairs, offsets, b2, bufB);

    // ---- pool + BN + linear ----
    pool_kernel<<<GG * PSLICE, 256, 0, stream>>>(bufB, start, pool);
    final_kernel<<<GG, 256, 0, stream>>>(pool, cnt, bn_g, bn_b, bn_m, bn_v, Wl, bl, out);
}